// Round 1
// baseline (4050.722 us; speedup 1.0000x reference)
//
#include <hip/hip_runtime.h>

#define NN 100000      // nodes
#define NE 1000000     // edges
#define NG 256         // graphs
#define IND 64
#define HD 146
#define EPSF 1e-5f

// ---------------- degree / counts ----------------
__global__ void k_deg(const int* __restrict__ src, const int* __restrict__ dst,
                      float* __restrict__ deg_out, float* __restrict__ deg_in) {
  int e = blockIdx.x * blockDim.x + threadIdx.x;
  if (e < NE) {
    atomicAdd(&deg_out[src[e]], 1.0f);
    atomicAdd(&deg_in[dst[e]], 1.0f);
  }
}

__global__ void k_invsqrt(float* __restrict__ a, int n) {
  int i = blockIdx.x * blockDim.x + threadIdx.x;
  if (i < n) a[i] = rsqrtf(fmaxf(a[i], 1.0f));
}

__global__ void k_counts(const int* __restrict__ gid, float* __restrict__ counts) {
  int i = blockIdx.x * blockDim.x + threadIdx.x;
  if (i < NN) atomicAdd(&counts[gid[i]], 1.0f);
}

// ---------------- embed GEMM: h = X @ W_e + b_e ----------------
__global__ __launch_bounds__(192) void k_embed(const float* __restrict__ X,
                                               const float* __restrict__ W,
                                               const float* __restrict__ b,
                                               float* __restrict__ h) {
  __shared__ float srow[IND];
  int row = blockIdx.x;
  int t = threadIdx.x;
  if (t < IND) srow[t] = X[row * IND + t];
  __syncthreads();
  if (t < HD) {
    float acc = b[t];
#pragma unroll
    for (int k = 0; k < IND; ++k) acc = fmaf(srow[k], W[k * HD + t], acc);
    h[row * HD + t] = acc;
  }
}

// ---------------- scatter: agg[dst] += h[src] * ns[src] ----------------
__global__ void k_scatter(const float* __restrict__ h, const float* __restrict__ ns,
                          const int* __restrict__ src, const int* __restrict__ dst,
                          float* __restrict__ agg) {
  const int total = NE * HD;  // 146,000,000 < INT_MAX
  int stride = gridDim.x * blockDim.x;
  for (int idx = blockIdx.x * blockDim.x + threadIdx.x; idx < total; idx += stride) {
    int e = idx / HD;
    int d = idx - e * HD;
    int s = src[e];
    int t = dst[e];
    atomicAdd(&agg[t * HD + d], h[s * HD + d] * ns[s]);
  }
}

// ---------------- layer GEMM in-place: agg = ((agg*nd) @ W + b) * snorm ----------------
__global__ __launch_bounds__(192) void k_gemm(float* __restrict__ agg,
                                              const float* __restrict__ nd,
                                              const float* __restrict__ W,
                                              const float* __restrict__ b,
                                              const float* __restrict__ snorm) {
  __shared__ float srow[HD];
  int row = blockIdx.x;
  int t = threadIdx.x;
  if (t < HD) srow[t] = agg[row * HD + t] * nd[row];
  __syncthreads();
  if (t < HD) {
    float acc = b[t];
#pragma unroll 2
    for (int k = 0; k < HD; ++k) acc = fmaf(srow[k], W[k * HD + t], acc);
    agg[row * HD + t] = acc * snorm[row];
  }
}

// ---------------- batchnorm stats: per-column sum & sumsq ----------------
__global__ __launch_bounds__(256) void k_bnstats(const float* __restrict__ h2,
                                                 float* __restrict__ stats) {
  int c = blockIdx.x;  // column
  int t = threadIdx.x;
  float s = 0.f, sq = 0.f;
  for (int r = t; r < NN; r += 256) {
    float v = h2[r * HD + c];
    s += v;
    sq += v * v;
  }
  __shared__ float ls[256], lq[256];
  ls[t] = s; lq[t] = sq;
  __syncthreads();
  for (int o = 128; o > 0; o >>= 1) {
    if (t < o) { ls[t] += ls[t + o]; lq[t] += lq[t + o]; }
    __syncthreads();
  }
  if (t == 0) { stats[c] = ls[0]; stats[HD + c] = lq[0]; }
}

__global__ void k_bnfinal(const float* __restrict__ stats, float* __restrict__ mi) {
  int c = threadIdx.x;
  if (c < HD) {
    float mean = stats[c] * (1.0f / NN);
    float var = stats[HD + c] * (1.0f / NN) - mean * mean;
    mi[c] = mean;
    mi[HD + c] = rsqrtf(var + EPSF);
  }
}

// ---------------- update: h += relu(bn(h2)) ----------------
__global__ void k_update(const float* __restrict__ h2, const float* __restrict__ mi,
                         const float* __restrict__ g, const float* __restrict__ bt,
                         float* __restrict__ h) {
  const int total = NN * HD;
  int stride = gridDim.x * blockDim.x;
  for (int idx = blockIdx.x * blockDim.x + threadIdx.x; idx < total; idx += stride) {
    int d = idx % HD;
    float v = (h2[idx] - mi[d]) * mi[HD + d] * g[d] + bt[d];
    h[idx] += fmaxf(v, 0.f);
  }
}

// ---------------- readout: out[gid[n]] += h[n]; then divide by counts ----------------
__global__ void k_readout(const float* __restrict__ h, const int* __restrict__ gid,
                          float* __restrict__ out) {
  const int total = NN * HD;
  int stride = gridDim.x * blockDim.x;
  for (int idx = blockIdx.x * blockDim.x + threadIdx.x; idx < total; idx += stride) {
    int n = idx / HD;
    int d = idx - n * HD;
    atomicAdd(&out[gid[n] * HD + d], h[idx]);
  }
}

__global__ void k_divide(float* __restrict__ out, const float* __restrict__ counts) {
  int i = blockIdx.x * blockDim.x + threadIdx.x;
  if (i < NG * HD) out[i] /= fmaxf(counts[i / HD], 1.0f);
}

extern "C" void kernel_launch(void* const* d_in, const int* in_sizes, int n_in,
                              void* d_out, int out_size, void* d_ws, size_t ws_size,
                              hipStream_t stream) {
  const float* X     = (const float*)d_in[0];
  const float* snorm = (const float*)d_in[1];
  const float* W_e   = (const float*)d_in[2];
  const float* b_e   = (const float*)d_in[3];
  const float* Wl[3]  = {(const float*)d_in[4], (const float*)d_in[8],  (const float*)d_in[12]};
  const float* bl[3]  = {(const float*)d_in[5], (const float*)d_in[9],  (const float*)d_in[13]};
  const float* gl[3]  = {(const float*)d_in[6], (const float*)d_in[10], (const float*)d_in[14]};
  const float* btl[3] = {(const float*)d_in[7], (const float*)d_in[11], (const float*)d_in[15]};
  const int* src = (const int*)d_in[16];
  const int* dst = (const int*)d_in[17];
  const int* gid = (const int*)d_in[18];
  float* out = (float*)d_out;

  char* ws = (char*)d_ws;
  float* h   = (float*)ws; ws += sizeof(float) * (size_t)NN * HD;
  float* agg = (float*)ws; ws += sizeof(float) * (size_t)NN * HD;
  float* ns  = (float*)ws; ws += sizeof(float) * (size_t)NN;   // deg_out -> ns
  float* nd  = (float*)ws; ws += sizeof(float) * (size_t)NN;   // deg_in  -> nd
  float* stats  = (float*)ws; ws += sizeof(float) * 4 * HD;    // sum, sumsq, mean, inv
  float* counts = (float*)ws; ws += sizeof(float) * NG;

  // zero accumulators
  hipMemsetAsync(ns, 0, sizeof(float) * 2 * (size_t)NN, stream);  // ns & nd contiguous
  hipMemsetAsync(counts, 0, sizeof(float) * NG, stream);
  hipMemsetAsync(out, 0, sizeof(float) * NG * HD, stream);

  k_deg<<<(NE + 255) / 256, 256, 0, stream>>>(src, dst, ns, nd);
  k_invsqrt<<<(2 * NN + 255) / 256, 256, 0, stream>>>(ns, 2 * NN);
  k_counts<<<(NN + 255) / 256, 256, 0, stream>>>(gid, counts);

  k_embed<<<NN, 192, 0, stream>>>(X, W_e, b_e, h);

  for (int l = 0; l < 3; ++l) {
    hipMemsetAsync(agg, 0, sizeof(float) * (size_t)NN * HD, stream);
    k_scatter<<<2048, 256, 0, stream>>>(h, ns, src, dst, agg);
    k_gemm<<<NN, 192, 0, stream>>>(agg, nd, Wl[l], bl[l], snorm);
    k_bnstats<<<HD, 256, 0, stream>>>(agg, stats);
    k_bnfinal<<<1, HD, 0, stream>>>(stats, stats + 2 * HD);
    k_update<<<2048, 256, 0, stream>>>(agg, stats + 2 * HD, gl[l], btl[l], h);
  }

  k_readout<<<2048, 256, 0, stream>>>(h, gid, out);
  k_divide<<<(NG * HD + 255) / 256, 256, 0, stream>>>(out, counts);
}

// Round 2
// 1628.742 us; speedup vs baseline: 2.4870x; 2.4870x over previous
//
#include <hip/hip_runtime.h>

#define NN 100000
#define NE 1000000
#define NG 256
#define IND 64
#define HD 146
#define EPSF 1e-5f
#define NSB 391   // ceil(NN/256)

// ---------------- degree histograms ----------------
__global__ void k_hist(const int* __restrict__ src, const int* __restrict__ dst,
                       int* __restrict__ cs, int* __restrict__ cd) {
  int e = blockIdx.x * 256 + threadIdx.x;
  if (e < NE) {
    atomicAdd(&cs[src[e]], 1);
    atomicAdd(&cd[dst[e]], 1);
  }
}

__global__ void k_norms(const int* __restrict__ cs, const int* __restrict__ cd,
                        float* __restrict__ ns, float* __restrict__ nd) {
  int i = blockIdx.x * 256 + threadIdx.x;
  if (i < NN) {
    ns[i] = rsqrtf(fmaxf((float)cs[i], 1.f));
    nd[i] = rsqrtf(fmaxf((float)cd[i], 1.f));
  }
}

// ---------------- exclusive scan of cd -> offs ----------------
__global__ void k_scan1(const int* __restrict__ cnt, int* __restrict__ offs,
                        int* __restrict__ part) {
  __shared__ int sm[256];
  int t = threadIdx.x, i = blockIdx.x * 256 + t;
  int v = (i < NN) ? cnt[i] : 0;
  sm[t] = v; __syncthreads();
  for (int o = 1; o < 256; o <<= 1) {
    int a = (t >= o) ? sm[t - o] : 0;
    __syncthreads();
    sm[t] += a;
    __syncthreads();
  }
  if (i < NN) offs[i] = sm[t] - v;
  if (t == 255) part[blockIdx.x] = sm[255];
}

__global__ void k_scan2(int* __restrict__ part) {
  __shared__ int sm[512];
  int t = threadIdx.x;
  int v = (t < NSB) ? part[t] : 0;
  sm[t] = v; __syncthreads();
  for (int o = 1; o < 512; o <<= 1) {
    int a = (t >= o) ? sm[t - o] : 0;
    __syncthreads();
    sm[t] += a;
    __syncthreads();
  }
  if (t < NSB) part[t] = sm[t] - v;
}

__global__ void k_scan3(int* __restrict__ offs, const int* __restrict__ part,
                        int* __restrict__ cur) {
  int i = blockIdx.x * 256 + threadIdx.x;
  if (i < NN) {
    int o = offs[i] + part[blockIdx.x];
    offs[i] = o;
    cur[i] = o;
  }
  if (i == 0) offs[NN] = NE;
}

__global__ void k_fill(const int* __restrict__ src, const int* __restrict__ dst,
                       int* __restrict__ cur, int* __restrict__ csr) {
  int e = blockIdx.x * 256 + threadIdx.x;
  if (e < NE) {
    int d = dst[e];
    int p = atomicAdd(&cur[d], 1);
    csr[p] = src[e];
  }
}

// ---------------- pull aggregation: agg[n] = nd[n] * sum_{s in in(n)} h[s]*ns[s] ----------------
__global__ __launch_bounds__(256) void k_pull(const float* __restrict__ h,
    const float* __restrict__ ns, const float* __restrict__ nd,
    const int* __restrict__ offs, const int* __restrict__ csr,
    float* __restrict__ agg) {
  int w = (blockIdx.x * 256 + threadIdx.x) >> 6;   // wave id = node
  int lane = threadIdx.x & 63;
  if (w >= NN) return;
  int lo = offs[w], hi = offs[w + 1];
  float a0 = 0.f, a1 = 0.f, a2 = 0.f;
  for (int j = lo; j < hi; ++j) {
    int s = __builtin_amdgcn_readfirstlane(csr[j]);   // wave-uniform -> SGPR base
    float wt = ns[s];
    const float* row = h + s * HD;
    a0 = fmaf(row[lane], wt, a0);
    a1 = fmaf(row[64 + lane], wt, a1);
    if (lane < HD - 128) a2 = fmaf(row[128 + lane], wt, a2);
  }
  float sc = nd[w];
  float* o = agg + w * HD;
  o[lane] = a0 * sc;
  o[64 + lane] = a1 * sc;
  if (lane < HD - 128) o[128 + lane] = a2 * sc;
}

// ---------------- pad W (K x 146) -> Wp (KE x 192, zero-padded, f4-aligned) ----------------
__global__ void k_padW(const float* __restrict__ W, float* __restrict__ Wp,
                       int K, int KE) {
  int idx = blockIdx.x * 256 + threadIdx.x;
  if (idx < KE * 192) {
    int k = idx / 192, c = idx - k * 192;
    Wp[idx] = (k < K && c < HD) ? W[k * HD + c] : 0.f;
  }
}

// ---------------- tiled GEMM: C[r][0..145] = A[r][:]@W + b (opt *snorm), in-place safe ----------------
template<int K, bool SNORM>
__global__ __launch_bounds__(256) void k_gemm(const float* __restrict__ A,
    const float* __restrict__ Wp, const float* __restrict__ bias,
    const float* __restrict__ snorm, float* __restrict__ C) {
  constexpr int PAD = (K == 64) ? 68 : 148;   // odd-mod-32 stride, f4-aligned
  constexpr int KE = (K + 3) & ~3;
  __shared__ __align__(16) float As[96 * PAD];
  int rb = blockIdx.x * 96;
  int t = threadIdx.x;
  int tx = t & 15, ty = t >> 4;               // 16 col-groups x 16 row-groups

  // stage 96 rows x K cols (zero-pad), coalesced global reads
  for (int idx = t; idx < 96 * PAD; idx += 256) {
    int r = idx / PAD, k = idx - r * PAD;
    int gr = rb + r;
    As[idx] = (k < K && gr < NN) ? A[gr * K + k] : 0.f;
  }
  __syncthreads();

  const float4* As4 = (const float4*)As;
  const float4* Wp4 = (const float4*)Wp;

#pragma unroll 1
  for (int cb = 0; cb < 3; ++cb) {
    float acc[6][4];
#pragma unroll
    for (int j = 0; j < 6; ++j)
#pragma unroll
      for (int c = 0; c < 4; ++c) acc[j][c] = 0.f;

    int cg = cb * 16 + tx;      // float4 col-group; col0 = 4*cg
#pragma unroll 1
    for (int k0 = 0; k0 < KE; k0 += 4) {
      float4 w0 = Wp4[(k0 + 0) * 48 + cg];
      float4 w1 = Wp4[(k0 + 1) * 48 + cg];
      float4 w2 = Wp4[(k0 + 2) * 48 + cg];
      float4 w3 = Wp4[(k0 + 3) * 48 + cg];
#pragma unroll
      for (int j = 0; j < 6; ++j) {
        float4 a = As4[(j * 16 + ty) * (PAD / 4) + (k0 >> 2)];
        acc[j][0] = fmaf(a.x, w0.x, fmaf(a.y, w1.x, fmaf(a.z, w2.x, fmaf(a.w, w3.x, acc[j][0]))));
        acc[j][1] = fmaf(a.x, w0.y, fmaf(a.y, w1.y, fmaf(a.z, w2.y, fmaf(a.w, w3.y, acc[j][1]))));
        acc[j][2] = fmaf(a.x, w0.z, fmaf(a.y, w1.z, fmaf(a.z, w2.z, fmaf(a.w, w3.z, acc[j][2]))));
        acc[j][3] = fmaf(a.x, w0.w, fmaf(a.y, w1.w, fmaf(a.z, w2.w, fmaf(a.w, w3.w, acc[j][3]))));
      }
    }

    int c0 = cg * 4;
#pragma unroll
    for (int j = 0; j < 6; ++j) {
      int row = rb + j * 16 + ty;
      if (row < NN) {
        float sn = SNORM ? snorm[row] : 1.f;
#pragma unroll
        for (int c = 0; c < 4; ++c) {
          int cc = c0 + c;
          if (cc < HD) {
            float v = acc[j][c] + bias[cc];
            if (SNORM) v *= sn;
            C[row * HD + cc] = v;
          }
        }
      }
    }
  }
}

// ---------------- batchnorm ----------------
__global__ __launch_bounds__(192) void k_bnstats(const float* __restrict__ h2,
                                                 float* __restrict__ st) {
  int c = threadIdx.x;
  if (c >= HD) return;
  float s = 0.f, q = 0.f;
  for (int r = blockIdx.x; r < NN; r += gridDim.x) {
    float v = h2[r * HD + c];
    s += v;
    q = fmaf(v, v, q);
  }
  atomicAdd(&st[c], s);
  atomicAdd(&st[HD + c], q);
}

__global__ void k_bnfinal(float* __restrict__ st) {
  int c = threadIdx.x;
  if (c < HD) {
    float m = st[c] * (1.f / NN);
    float var = st[HD + c] * (1.f / NN) - m * m;
    st[2 * HD + c] = m;
    st[3 * HD + c] = rsqrtf(var + EPSF);
  }
}

__global__ __launch_bounds__(192) void k_update(const float* __restrict__ h2,
    const float* __restrict__ st, const float* __restrict__ g,
    const float* __restrict__ bt, float* __restrict__ h) {
  int c = threadIdx.x;
  if (c >= HD) return;
  float m = st[2 * HD + c], iv = st[3 * HD + c], gg = g[c], bb = bt[c];
  for (int r = blockIdx.x; r < NN; r += gridDim.x) {
    float v = (h2[r * HD + c] - m) * iv * gg + bb;
    h[r * HD + c] += fmaxf(v, 0.f);
  }
}

// ---------------- readout: block-per-graph (graph_ids sorted) ----------------
__device__ inline int lbound(const int* __restrict__ a, int key) {
  int lo = 0, hi = NN;
  while (lo < hi) {
    int m = (lo + hi) >> 1;
    if (a[m] < key) lo = m + 1; else hi = m;
  }
  return lo;
}

__global__ __launch_bounds__(192) void k_readout(const float* __restrict__ h,
    const int* __restrict__ gid, float* __restrict__ out) {
  int g = blockIdx.x;
  int lo = lbound(gid, g), hi = lbound(gid, g + 1);
  int c = threadIdx.x;
  if (c >= HD) return;
  float s = 0.f;
  for (int r = lo; r < hi; ++r) s += h[r * HD + c];
  out[g * HD + c] = s / fmaxf((float)(hi - lo), 1.f);
}

extern "C" void kernel_launch(void* const* d_in, const int* in_sizes, int n_in,
                              void* d_out, int out_size, void* d_ws, size_t ws_size,
                              hipStream_t stream) {
  const float* X     = (const float*)d_in[0];
  const float* snorm = (const float*)d_in[1];
  const float* W_e   = (const float*)d_in[2];
  const float* b_e   = (const float*)d_in[3];
  const float* Wl[3]  = {(const float*)d_in[4], (const float*)d_in[8],  (const float*)d_in[12]};
  const float* bl[3]  = {(const float*)d_in[5], (const float*)d_in[9],  (const float*)d_in[13]};
  const float* gl[3]  = {(const float*)d_in[6], (const float*)d_in[10], (const float*)d_in[14]};
  const float* btl[3] = {(const float*)d_in[7], (const float*)d_in[11], (const float*)d_in[15]};
  const int* src = (const int*)d_in[16];
  const int* dst = (const int*)d_in[17];
  const int* gid = (const int*)d_in[18];
  float* out = (float*)d_out;

  char* p = (char*)d_ws;
  float* h   = (float*)p; p += sizeof(float) * (size_t)NN * HD;
  float* agg = (float*)p; p += sizeof(float) * (size_t)NN * HD;
  float* ns  = (float*)p; p += sizeof(float) * NN;
  float* nd  = (float*)p; p += sizeof(float) * NN;
  float* Wp  = (float*)p; p += sizeof(float) * 148 * 192;
  float* st  = (float*)p; p += sizeof(float) * 4 * HD;
  int* cs   = (int*)p; p += sizeof(int) * NN;
  int* cd   = (int*)p; p += sizeof(int) * NN;
  int* offs = (int*)p; p += sizeof(int) * (NN + 1);
  int* cur  = (int*)p; p += sizeof(int) * NN;
  int* part = (int*)p; p += sizeof(int) * 512;
  int* csr  = (int*)p; p += sizeof(int) * NE;

  hipMemsetAsync(cs, 0, sizeof(int) * 2 * (size_t)NN, stream);  // cs & cd contiguous

  k_hist <<<(NE + 255) / 256, 256, 0, stream>>>(src, dst, cs, cd);
  k_norms<<<NSB, 256, 0, stream>>>(cs, cd, ns, nd);
  k_scan1<<<NSB, 256, 0, stream>>>(cd, offs, part);
  k_scan2<<<1, 512, 0, stream>>>(part);
  k_scan3<<<NSB, 256, 0, stream>>>(offs, part, cur);
  k_fill <<<(NE + 255) / 256, 256, 0, stream>>>(src, dst, cur, csr);

  // embed: h = X @ W_e + b_e
  k_padW<<<(64 * 192 + 255) / 256, 256, 0, stream>>>(W_e, Wp, IND, 64);
  k_gemm<64, false><<<(NN + 95) / 96, 256, 0, stream>>>(X, Wp, b_e, nullptr, h);

  for (int l = 0; l < 3; ++l) {
    k_pull<<<(NN * 64 + 255) / 256, 256, 0, stream>>>(h, ns, nd, offs, csr, agg);
    k_padW<<<(148 * 192 + 255) / 256, 256, 0, stream>>>(Wl[l], Wp, HD, 148);
    k_gemm<HD, true><<<(NN + 95) / 96, 256, 0, stream>>>(agg, Wp, bl[l], snorm, agg);
    hipMemsetAsync(st, 0, sizeof(float) * 2 * HD, stream);
    k_bnstats<<<512, 192, 0, stream>>>(agg, st);
    k_bnfinal<<<1, 192, 0, stream>>>(st);
    k_update<<<1024, 192, 0, stream>>>(agg, st, gl[l], btl[l], h);
  }

  k_readout<<<NG, 192, 0, stream>>>(h, gid, out);
}

// Round 3
// 1198.268 us; speedup vs baseline: 3.3805x; 1.3592x over previous
//
#include <hip/hip_runtime.h>

#define NN 100000
#define NE 1000000
#define NG 256
#define HD 146
#define SP 148          // padded row stride (floats), 37 float4s
#define SP4 37
#define EPSF 1e-5f
#define NSB 391         // ceil(NN/256)

// ---------------- degree histograms ----------------
__global__ void k_hist(const int* __restrict__ src, const int* __restrict__ dst,
                       int* __restrict__ cs, int* __restrict__ cd) {
  int e = blockIdx.x * 256 + threadIdx.x;
  if (e < NE) {
    atomicAdd(&cs[src[e]], 1);
    atomicAdd(&cd[dst[e]], 1);
  }
}

__global__ void k_norms(const int* __restrict__ cs, const int* __restrict__ cd,
                        float* __restrict__ ns, float* __restrict__ nd) {
  int i = blockIdx.x * 256 + threadIdx.x;
  if (i < NN) {
    ns[i] = rsqrtf(fmaxf((float)cs[i], 1.f));
    nd[i] = rsqrtf(fmaxf((float)cd[i], 1.f));
  }
}

// ---------------- exclusive scan of cd -> offs ----------------
__global__ void k_scan1(const int* __restrict__ cnt, int* __restrict__ offs,
                        int* __restrict__ part) {
  __shared__ int sm[256];
  int t = threadIdx.x, i = blockIdx.x * 256 + t;
  int v = (i < NN) ? cnt[i] : 0;
  sm[t] = v; __syncthreads();
  for (int o = 1; o < 256; o <<= 1) {
    int a = (t >= o) ? sm[t - o] : 0;
    __syncthreads();
    sm[t] += a;
    __syncthreads();
  }
  if (i < NN) offs[i] = sm[t] - v;
  if (t == 255) part[blockIdx.x] = sm[255];
}

__global__ void k_scan2(int* __restrict__ part) {
  __shared__ int sm[512];
  int t = threadIdx.x;
  int v = (t < NSB) ? part[t] : 0;
  sm[t] = v; __syncthreads();
  for (int o = 1; o < 512; o <<= 1) {
    int a = (t >= o) ? sm[t - o] : 0;
    __syncthreads();
    sm[t] += a;
    __syncthreads();
  }
  if (t < NSB) part[t] = sm[t] - v;
}

__global__ void k_scan3(int* __restrict__ offs, const int* __restrict__ part,
                        int* __restrict__ cur) {
  int i = blockIdx.x * 256 + threadIdx.x;
  if (i < NN) {
    int o = offs[i] + part[blockIdx.x];
    offs[i] = o;
    cur[i] = o;
  }
  if (i == 0) offs[NN] = NE;
}

__global__ void k_fill(const int* __restrict__ src, const int* __restrict__ dst,
                       int* __restrict__ cur, int* __restrict__ csr) {
  int e = blockIdx.x * 256 + threadIdx.x;
  if (e < NE) {
    int d = dst[e];
    int p = atomicAdd(&cur[d], 1);
    csr[p] = src[e];
  }
}

// ---------------- pull aggregation (stride SP) ----------------
__global__ __launch_bounds__(256) void k_pull(const float* __restrict__ h,
    const float* __restrict__ ns, const float* __restrict__ nd,
    const int* __restrict__ offs, const int* __restrict__ csr,
    float* __restrict__ agg) {
  int w = (blockIdx.x * 256 + threadIdx.x) >> 6;
  int lane = threadIdx.x & 63;
  if (w >= NN) return;
  int lo = offs[w], hi = offs[w + 1];
  float a0 = 0.f, a1 = 0.f, a2 = 0.f;
  for (int j = lo; j < hi; ++j) {
    int s = __builtin_amdgcn_readfirstlane(csr[j]);
    float wt = ns[s];
    const float* row = h + (size_t)s * SP;
    a0 = fmaf(row[lane], wt, a0);
    a1 = fmaf(row[64 + lane], wt, a1);
    if (lane < HD - 128) a2 = fmaf(row[128 + lane], wt, a2);
  }
  float sc = nd[w];
  float* o = agg + (size_t)w * SP;
  o[lane] = a0 * sc;
  o[64 + lane] = a1 * sc;
  if (lane < HD - 128) o[128 + lane] = a2 * sc;
}

// ---------------- pad W (KREAL x 146) -> Wp (KPAD x 192, zeros) ----------------
__global__ void k_padW(const float* __restrict__ W, float* __restrict__ Wp,
                       int KREAL, int KPAD) {
  int idx = blockIdx.x * 256 + threadIdx.x;
  if (idx < KPAD * 192) {
    int k = idx / 192, c = idx - k * 192;
    Wp[idx] = (k < KREAL && c < HD) ? W[k * HD + c] : 0.f;
  }
}

__global__ void k_padb(const float* __restrict__ b, float* __restrict__ bp) {
  int t = threadIdx.x;
  if (t < 192) bp[t] = (t < HD) ? b[t] : 0.f;
}

// ---------------- tiled GEMM: C = A @ Wp + bp [*snorm], fused BN partial stats ----
// A: row stride K4 float4s; C: row stride SP4 float4s. In-place safe (block owns rows).
template<int K4, int NCHUNK, bool STATS, bool SNORM>
__global__ __launch_bounds__(256, 2) void k_gemm2(const float* __restrict__ A,
    const float* __restrict__ Wp, const float* __restrict__ bp,
    const float* __restrict__ snorm, float* __restrict__ C, float* __restrict__ st) {
  __shared__ float As[32 * 128];        // [k][r] transposed
  __shared__ float Ws[32 * 192];        // [k][c]
  __shared__ float bsum[192], bsq[192];
  int t = threadIdx.x;
  int tx = t & 15, ty = t >> 4;
  int rb = blockIdx.x * 128;

  if (STATS && t < 192) { bsum[t] = 0.f; bsq[t] = 0.f; }

  float acc[8][12];
#pragma unroll
  for (int j = 0; j < 8; ++j)
#pragma unroll
    for (int c = 0; c < 12; ++c) acc[j][c] = 0.f;

  const float4* A4 = (const float4*)A;
  const float4* Wp4 = (const float4*)Wp;
  const float4* As4 = (const float4*)As;
  const float4* Ws4 = (const float4*)Ws;

#pragma unroll 1
  for (int kt = 0; kt < NCHUNK; ++kt) {
    // stage A: 128 rows x 32 k (transposed into As[k][r])
    int kb4 = kt * 8;
#pragma unroll
    for (int ii = 0; ii < 4; ++ii) {
      int i = t + ii * 256;
      int kg = i & 7, r = i >> 3;
      int gr = rb + r;
      int kq = kb4 + kg;
      float4 v = make_float4(0.f, 0.f, 0.f, 0.f);
      if (gr < NN && kq < K4) v = A4[(size_t)gr * K4 + kq];
      int kl = kg * 4;
      As[(kl + 0) * 128 + r] = v.x;
      As[(kl + 1) * 128 + r] = v.y;
      As[(kl + 2) * 128 + r] = v.z;
      As[(kl + 3) * 128 + r] = v.w;
    }
    // stage W: 32 k x 192 cols
#pragma unroll
    for (int ii = 0; ii < 6; ++ii) {
      int i = t + ii * 256;
      ((float4*)Ws)[i] = Wp4[kt * 1536 + i];
    }
    __syncthreads();

#pragma unroll 2
    for (int kk = 0; kk < 32; ++kk) {
      float4 a0 = As4[kk * 32 + ty * 2];
      float4 a1 = As4[kk * 32 + ty * 2 + 1];
      float4 w0 = Ws4[kk * 48 + tx];
      float4 w1 = Ws4[kk * 48 + 16 + tx];
      float4 w2 = Ws4[kk * 48 + 32 + tx];
      float ar[8] = {a0.x, a0.y, a0.z, a0.w, a1.x, a1.y, a1.z, a1.w};
#pragma unroll
      for (int j = 0; j < 8; ++j) {
        acc[j][0]  = fmaf(ar[j], w0.x, acc[j][0]);
        acc[j][1]  = fmaf(ar[j], w0.y, acc[j][1]);
        acc[j][2]  = fmaf(ar[j], w0.z, acc[j][2]);
        acc[j][3]  = fmaf(ar[j], w0.w, acc[j][3]);
        acc[j][4]  = fmaf(ar[j], w1.x, acc[j][4]);
        acc[j][5]  = fmaf(ar[j], w1.y, acc[j][5]);
        acc[j][6]  = fmaf(ar[j], w1.z, acc[j][6]);
        acc[j][7]  = fmaf(ar[j], w1.w, acc[j][7]);
        acc[j][8]  = fmaf(ar[j], w2.x, acc[j][8]);
        acc[j][9]  = fmaf(ar[j], w2.y, acc[j][9]);
        acc[j][10] = fmaf(ar[j], w2.z, acc[j][10]);
        acc[j][11] = fmaf(ar[j], w2.w, acc[j][11]);
      }
    }
    __syncthreads();
  }

  // epilogue: bias (+snorm), store, fused BN partial sums
  float cs[12], cq[12];
#pragma unroll
  for (int c = 0; c < 12; ++c) { cs[c] = 0.f; cq[c] = 0.f; }

  float4* C4 = (float4*)C;
#pragma unroll
  for (int j = 0; j < 8; ++j) {
    int row = rb + ty * 8 + j;
    if (row < NN) {
      float sn = SNORM ? snorm[row] : 1.f;
#pragma unroll
      for (int g = 0; g < 3; ++g) {
        int grp = tx + 16 * g;
        float4 v;
        v.x = acc[j][g * 4 + 0] + bp[grp * 4 + 0];
        v.y = acc[j][g * 4 + 1] + bp[grp * 4 + 1];
        v.z = acc[j][g * 4 + 2] + bp[grp * 4 + 2];
        v.w = acc[j][g * 4 + 3] + bp[grp * 4 + 3];
        if (SNORM) { v.x *= sn; v.y *= sn; v.z *= sn; v.w *= sn; }
        if (grp < SP4) C4[(size_t)row * SP4 + grp] = v;
        if (STATS) {
          cs[g * 4 + 0] += v.x; cq[g * 4 + 0] = fmaf(v.x, v.x, cq[g * 4 + 0]);
          cs[g * 4 + 1] += v.y; cq[g * 4 + 1] = fmaf(v.y, v.y, cq[g * 4 + 1]);
          cs[g * 4 + 2] += v.z; cq[g * 4 + 2] = fmaf(v.z, v.z, cq[g * 4 + 2]);
          cs[g * 4 + 3] += v.w; cq[g * 4 + 3] = fmaf(v.w, v.w, cq[g * 4 + 3]);
        }
      }
    }
  }
  if (STATS) {
#pragma unroll
    for (int c = 0; c < 12; ++c) {
      int col = tx * 4 + (c / 4) * 64 + (c & 3);
      atomicAdd(&bsum[col], cs[c]);
      atomicAdd(&bsq[col], cq[c]);
    }
    __syncthreads();
    if (t < 192) {
      atomicAdd(&st[t], bsum[t]);
      atomicAdd(&st[192 + t], bsq[t]);
    }
  }
}

// ---------------- update: h += relu(bn(h2)) (bnfinal folded in) ----------------
__global__ __launch_bounds__(192) void k_update(const float* __restrict__ h2,
    const float* __restrict__ st, const float* __restrict__ g,
    const float* __restrict__ bt, float* __restrict__ h) {
  int c = threadIdx.x;
  if (c >= HD) return;
  float m = st[c] * (1.f / NN);
  float q = st[192 + c] * (1.f / NN);
  float iv = rsqrtf(q - m * m + EPSF);
  float a = iv * g[c];
  float b2 = bt[c] - m * a;
  for (int r = blockIdx.x; r < NN; r += gridDim.x) {
    float v = fmaf(h2[(size_t)r * SP + c], a, b2);
    h[(size_t)r * SP + c] += fmaxf(v, 0.f);
  }
}

// ---------------- readout: block-per-graph (graph_ids sorted) ----------------
__device__ inline int lbound(const int* __restrict__ a, int key) {
  int lo = 0, hi = NN;
  while (lo < hi) {
    int m = (lo + hi) >> 1;
    if (a[m] < key) lo = m + 1; else hi = m;
  }
  return lo;
}

__global__ __launch_bounds__(192) void k_readout(const float* __restrict__ h,
    const int* __restrict__ gid, float* __restrict__ out) {
  int g = blockIdx.x;
  int lo = lbound(gid, g), hi = lbound(gid, g + 1);
  int c = threadIdx.x;
  if (c >= HD) return;
  float s = 0.f;
  for (int r = lo; r < hi; ++r) s += h[(size_t)r * SP + c];
  out[g * HD + c] = s / fmaxf((float)(hi - lo), 1.f);
}

extern "C" void kernel_launch(void* const* d_in, const int* in_sizes, int n_in,
                              void* d_out, int out_size, void* d_ws, size_t ws_size,
                              hipStream_t stream) {
  const float* X     = (const float*)d_in[0];
  const float* snorm = (const float*)d_in[1];
  const float* W_e   = (const float*)d_in[2];
  const float* b_e   = (const float*)d_in[3];
  const float* Wl[3]  = {(const float*)d_in[4], (const float*)d_in[8],  (const float*)d_in[12]};
  const float* bl[3]  = {(const float*)d_in[5], (const float*)d_in[9],  (const float*)d_in[13]};
  const float* gl[3]  = {(const float*)d_in[6], (const float*)d_in[10], (const float*)d_in[14]};
  const float* btl[3] = {(const float*)d_in[7], (const float*)d_in[11], (const float*)d_in[15]};
  const int* src = (const int*)d_in[16];
  const int* dst = (const int*)d_in[17];
  const int* gid = (const int*)d_in[18];
  float* out = (float*)d_out;

  char* p = (char*)d_ws;
  float* h   = (float*)p; p += sizeof(float) * (size_t)NN * SP;
  float* agg = (float*)p; p += sizeof(float) * (size_t)NN * SP;
  float* ns  = (float*)p; p += sizeof(float) * NN;
  float* nd  = (float*)p; p += sizeof(float) * NN;
  float* Wp  = (float*)p; p += sizeof(float) * 160 * 192;
  float* bp  = (float*)p; p += sizeof(float) * 192;
  float* st  = (float*)p; p += sizeof(float) * 2 * 192;
  int* cs   = (int*)p; p += sizeof(int) * NN;
  int* cd   = (int*)p; p += sizeof(int) * NN;
  int* offs = (int*)p; p += sizeof(int) * (NN + 1);
  int* cur  = (int*)p; p += sizeof(int) * NN;
  int* part = (int*)p; p += sizeof(int) * 512;
  int* csr  = (int*)p; p += sizeof(int) * NE;

  hipMemsetAsync(cs, 0, sizeof(int) * 2 * (size_t)NN, stream);

  k_hist <<<(NE + 255) / 256, 256, 0, stream>>>(src, dst, cs, cd);
  k_norms<<<NSB, 256, 0, stream>>>(cs, cd, ns, nd);
  k_scan1<<<NSB, 256, 0, stream>>>(cd, offs, part);
  k_scan2<<<1, 512, 0, stream>>>(part);
  k_scan3<<<NSB, 256, 0, stream>>>(offs, part, cur);
  k_fill <<<(NE + 255) / 256, 256, 0, stream>>>(src, dst, cur, csr);

  const int GB = (NN + 127) / 128;   // 782 gemm blocks

  // embed: h = X @ W_e + b_e   (K=64 -> 2 chunks, A stride 16 f4)
  k_padW<<<(64 * 192 + 255) / 256, 256, 0, stream>>>(W_e, Wp, 64, 64);
  k_padb<<<1, 192, 0, stream>>>(b_e, bp);
  k_gemm2<16, 2, false, false><<<GB, 256, 0, stream>>>(X, Wp, bp, nullptr, h, nullptr);

  for (int l = 0; l < 3; ++l) {
    k_pull<<<(NN * 64 + 255) / 256, 256, 0, stream>>>(h, ns, nd, offs, csr, agg);
    k_padW<<<(160 * 192 + 255) / 256, 256, 0, stream>>>(Wl[l], Wp, HD, 160);
    k_padb<<<1, 192, 0, stream>>>(bl[l], bp);
    hipMemsetAsync(st, 0, sizeof(float) * 2 * 192, stream);
    k_gemm2<SP4, 5, true, true><<<GB, 256, 0, stream>>>(agg, Wp, bp, snorm, agg, st);
    k_update<<<1024, 192, 0, stream>>>(agg, st, gl[l], btl[l], h);
  }

  k_readout<<<NG, 192, 0, stream>>>(h, gid, out);
}

// Round 4
// 1043.064 us; speedup vs baseline: 3.8835x; 1.1488x over previous
//
#include <hip/hip_runtime.h>

#define NN 100000
#define NE 1000000
#define NG 256
#define HD 146
#define SP 148          // fp32 h row stride
#define EPSF 1e-5f
#define NSB 391         // ceil(NN/256)
#define NRB 6250        // NN/16 row-blocks (exact)

typedef _Float16 f16;
typedef f16 f16x8 __attribute__((ext_vector_type(8)));
typedef f16 f16x2 __attribute__((ext_vector_type(2)));
typedef float f32x4 __attribute__((ext_vector_type(4)));

// ---------------- degree histograms ----------------
__global__ void k_hist(const int* __restrict__ src, const int* __restrict__ dst,
                       int* __restrict__ cs, int* __restrict__ cd) {
  int e = blockIdx.x * 256 + threadIdx.x;
  if (e < NE) {
    atomicAdd(&cs[src[e]], 1);
    atomicAdd(&cd[dst[e]], 1);
  }
}

__global__ void k_norms(const int* __restrict__ cs, const int* __restrict__ cd,
                        float* __restrict__ ns, float* __restrict__ nd) {
  int i = blockIdx.x * 256 + threadIdx.x;
  if (i < NN) {
    ns[i] = rsqrtf(fmaxf((float)cs[i], 1.f));
    nd[i] = rsqrtf(fmaxf((float)cd[i], 1.f));
  }
}

// ---------------- exclusive scan of cd -> offs ----------------
__global__ void k_scan1(const int* __restrict__ cnt, int* __restrict__ offs,
                        int* __restrict__ part) {
  __shared__ int sm[256];
  int t = threadIdx.x, i = blockIdx.x * 256 + t;
  int v = (i < NN) ? cnt[i] : 0;
  sm[t] = v; __syncthreads();
  for (int o = 1; o < 256; o <<= 1) {
    int a = (t >= o) ? sm[t - o] : 0;
    __syncthreads();
    sm[t] += a;
    __syncthreads();
  }
  if (i < NN) offs[i] = sm[t] - v;
  if (t == 255) part[blockIdx.x] = sm[255];
}

__global__ void k_scan2(int* __restrict__ part) {
  __shared__ int sm[512];
  int t = threadIdx.x;
  int v = (t < NSB) ? part[t] : 0;
  sm[t] = v; __syncthreads();
  for (int o = 1; o < 512; o <<= 1) {
    int a = (t >= o) ? sm[t - o] : 0;
    __syncthreads();
    sm[t] += a;
    __syncthreads();
  }
  if (t < NSB) part[t] = sm[t] - v;
}

__global__ void k_scan3(int* __restrict__ offs, const int* __restrict__ part,
                        int* __restrict__ cur) {
  int i = blockIdx.x * 256 + threadIdx.x;
  if (i < NN) {
    int o = offs[i] + part[blockIdx.x];
    offs[i] = o;
    cur[i] = o;
  }
  if (i == 0) offs[NN] = NE;
}

__global__ void k_fill(const int* __restrict__ src, const int* __restrict__ dst,
                       int* __restrict__ cur, int* __restrict__ csr) {
  int e = blockIdx.x * 256 + threadIdx.x;
  if (e < NE) {
    int d = dst[e];
    int p = atomicAdd(&cur[d], 1);
    csr[p] = src[e];
  }
}

// ---------------- pull: agg_tiled[n] = nd[n]*sum h_half[s]*ns[s] ----------------
// hh: half [NN][146]; aggt: tiled half [NRB][20][16][8]
__global__ __launch_bounds__(256) void k_pull(const f16* __restrict__ hh,
    const float* __restrict__ ns, const float* __restrict__ nd,
    const int* __restrict__ offs, const int* __restrict__ csr,
    f16* __restrict__ aggt) {
  int wid = (blockIdx.x * 256 + threadIdx.x) >> 6;
  int l = threadIdx.x & 63;
  if (wid >= NN) return;
  int lo = offs[wid], hi = offs[wid + 1];
  float a0 = 0.f, a1 = 0.f, b0 = 0.f, b1 = 0.f;
  for (int e = lo; e < hi; ++e) {
    int s = __builtin_amdgcn_readfirstlane(csr[e]);
    float wt = ns[s];
    const f16* row = hh + (size_t)s * HD;
    f16x2 v = *(const f16x2*)(row + 2 * l);
    a0 = fmaf((float)v[0], wt, a0);
    a1 = fmaf((float)v[1], wt, a1);
    if (l < 9) {   // cols 128..145
      f16x2 u = *(const f16x2*)(row + 128 + 2 * l);
      b0 = fmaf((float)u[0], wt, b0);
      b1 = fmaf((float)u[1], wt, b1);
    }
  }
  float sc = nd[wid];
  int B = wid >> 4, pos = wid & 15;
  int c = 2 * l;
  size_t off = ((size_t)B * 20 + (c >> 3)) * 128 + pos * 8 + (c & 7);
  f16x2 w0; w0[0] = (f16)(a0 * sc); w0[1] = (f16)(a1 * sc);
  *(f16x2*)(aggt + off) = w0;
  if (l < 16) {
    int cc = 128 + 2 * l;
    size_t off2 = ((size_t)B * 20 + (cc >> 3)) * 128 + pos * 8 + (cc & 7);
    f16x2 w1;
    w1[0] = (cc < HD) ? (f16)(b0 * sc) : (f16)0;
    w1[1] = (cc + 1 < HD) ? (f16)(b1 * sc) : (f16)0;
    *(f16x2*)(aggt + off2) = w1;
  }
}

// ---------------- weight/bias/X prep into tiled f16 layouts ----------------
// layer W [146][146] -> Wt [10 cb][20 kg][16 pos][8 j]
__global__ void k_padW(const float* __restrict__ W, f16* __restrict__ Wt) {
  int idx = blockIdx.x * 256 + threadIdx.x;
  if (idx >= 25600) return;
  int j = idx & 7, pos = (idx >> 3) & 15;
  int rem = idx >> 7;
  int kg = rem % 20, cb = rem / 20;
  int c = cb * 16 + pos, k = kg * 8 + j;
  Wt[idx] = (k < HD && c < HD) ? (f16)W[k * HD + c] : (f16)0;
}

// embed W_e [64][146] -> Wt [10 cb][8 kg][16 pos][8 j]
__global__ void k_padWe(const float* __restrict__ W, f16* __restrict__ Wt) {
  int idx = blockIdx.x * 256 + threadIdx.x;
  if (idx >= 10240) return;
  int j = idx & 7, pos = (idx >> 3) & 15;
  int rem = idx >> 7;
  int kg = rem & 7, cb = rem >> 3;
  int c = cb * 16 + pos, k = kg * 8 + j;
  Wt[idx] = (c < HD) ? (f16)W[k * HD + c] : (f16)0;
}

__global__ void k_padb(const float* __restrict__ b, float* __restrict__ bp) {
  int t = threadIdx.x;
  if (t < 160) bp[t] = (t < HD) ? b[t] : 0.f;
}

// X fp32 [NN][64] -> Xt tiled [NRB][8 kg][16 pos][8 j]
__global__ void k_convX(const float* __restrict__ X, f16* __restrict__ Xt) {
  int i = blockIdx.x * 256 + threadIdx.x;   // item = 8 halves
  if (i >= NRB * 8 * 16) return;
  int pos = i & 15, kg = (i >> 4) & 7, RB = i >> 7;
  const float* src = X + ((size_t)RB * 16 + pos) * 64 + kg * 8;
  f16x8 v;
#pragma unroll
  for (int j = 0; j < 8; ++j) v[j] = (f16)src[j];
  *(f16x8*)(Xt + (size_t)i * 8) = v;
}

// ---------------- MFMA GEMM ----------------
// A tiled [NRB][KG][16][8], W tiled [10][KG][16][8]; BM=128, BN=160, 4 waves (2x2).
// LAYER: out h2 half row-major [NN][160] (+bias,*snorm, fused BN stats)
// !LAYER: out h fp32 [NN][SP] cols<146 (+bias) and hh half [NN][146]
template<int KG, int NSTEP, bool LAYER>
__global__ __launch_bounds__(256) void k_mfma(
    const f16* __restrict__ At, const f16* __restrict__ Wt,
    const float* __restrict__ bp, const float* __restrict__ snorm,
    float* __restrict__ Cf, f16* __restrict__ Hh,
    f16* __restrict__ Ch, float* __restrict__ st) {
  __shared__ __align__(16) f16 As[8 * 512];
  __shared__ __align__(16) f16 Ws[10 * 512];
  __shared__ float bsum[160], bsq[160];

  int t = threadIdx.x;
  int w = t >> 6, l = t & 63;
  int wr = w >> 1, wc = w & 1;
  int l15 = l & 15, l4 = l >> 4;
  int RB0 = blockIdx.x * 8;

  if (LAYER && t < 160) { bsum[t] = 0.f; bsq[t] = 0.f; }

  f32x4 acc[4][5];
#pragma unroll
  for (int i = 0; i < 4; ++i)
#pragma unroll
    for (int j = 0; j < 5; ++j) acc[i][j] = (f32x4)0.f;

#pragma unroll 1
  for (int s = 0; s < NSTEP; ++s) {
    __syncthreads();
    // stage A: 8 chunks x 64 items of 16B
#pragma unroll
    for (int u = 0; u < 2; ++u) {
      int i = t + u * 256;
      int rb = i >> 6, p = i & 63;
      int RB = RB0 + rb;
      f16x8 v = (f16x8)(f16)0;
      if (RB < NRB) v = *(const f16x8*)(At + ((size_t)RB * KG + 4 * s) * 128 + p * 8);
      *(f16x8*)(As + rb * 512 + p * 8) = v;
    }
    // stage W: 10 chunks x 64 items
#pragma unroll
    for (int u = 0; u < 3; ++u) {
      int m = t + u * 256;
      if (m < 640) {
        int cb = m >> 6, p = m & 63;
        f16x8 v = *(const f16x8*)(Wt + ((size_t)cb * KG + 4 * s) * 128 + p * 8);
        *(f16x8*)(Ws + cb * 512 + p * 8) = v;
      }
    }
    __syncthreads();

    f16x8 af[4], bf[5];
#pragma unroll
    for (int i = 0; i < 4; ++i)
      af[i] = *(const f16x8*)(As + (wr * 4 + i) * 512 + l4 * 128 + l15 * 8);
#pragma unroll
    for (int j = 0; j < 5; ++j)
      bf[j] = *(const f16x8*)(Ws + (wc * 5 + j) * 512 + l4 * 128 + l15 * 8);
#pragma unroll
    for (int i = 0; i < 4; ++i)
#pragma unroll
      for (int j = 0; j < 5; ++j)
        acc[i][j] = __builtin_amdgcn_mfma_f32_16x16x32_f16(af[i], bf[j], acc[i][j], 0, 0, 0);
  }

  // epilogue
  float cs[5], cq[5];
#pragma unroll
  for (int j = 0; j < 5; ++j) { cs[j] = 0.f; cq[j] = 0.f; }

  int colbase = wc * 80;
  int rowbase = RB0 * 16 + wr * 64;
#pragma unroll
  for (int i = 0; i < 4; ++i) {
#pragma unroll
    for (int r = 0; r < 4; ++r) {
      int row = rowbase + i * 16 + l4 * 4 + r;
      bool ok = row < NN;
      float sn = 1.f;
      if (LAYER && ok) sn = snorm[row];
#pragma unroll
      for (int j = 0; j < 5; ++j) {
        int col = colbase + j * 16 + l15;
        float v = acc[i][j][r] + bp[col];
        if (LAYER) {
          v *= sn;
          if (ok) {
            Ch[(size_t)row * 160 + col] = (f16)v;
            cs[j] += v;
            cq[j] = fmaf(v, v, cq[j]);
          }
        } else {
          if (ok && col < HD) {
            Cf[(size_t)row * SP + col] = v;
            Hh[(size_t)row * HD + col] = (f16)v;
          }
        }
      }
    }
  }
  if (LAYER) {
#pragma unroll
    for (int j = 0; j < 5; ++j) {
      int col = colbase + j * 16 + l15;
      atomicAdd(&bsum[col], cs[j]);
      atomicAdd(&bsq[col], cq[j]);
    }
    __syncthreads();
    if (t < 160) {
      atomicAdd(&st[t], bsum[t]);
      atomicAdd(&st[160 + t], bsq[t]);
    }
  }
}

// ---------------- update: h += relu(bn(h2)); hh = half(h) ----------------
__global__ __launch_bounds__(192) void k_update(const f16* __restrict__ h2,
    const float* __restrict__ st, const float* __restrict__ g,
    const float* __restrict__ bt, float* __restrict__ h, f16* __restrict__ hh) {
  int c = threadIdx.x;
  if (c >= HD) return;
  float m = st[c] * (1.f / NN);
  float q = st[160 + c] * (1.f / NN);
  float iv = rsqrtf(q - m * m + EPSF);
  float a = iv * g[c];
  float b2 = bt[c] - m * a;
  for (int r = blockIdx.x; r < NN; r += gridDim.x) {
    float v = fmaf((float)h2[(size_t)r * 160 + c], a, b2);
    float hn = h[(size_t)r * SP + c] + fmaxf(v, 0.f);
    h[(size_t)r * SP + c] = hn;
    hh[(size_t)r * HD + c] = (f16)hn;
  }
}

// ---------------- readout ----------------
__device__ inline int lbound(const int* __restrict__ a, int key) {
  int lo = 0, hi = NN;
  while (lo < hi) {
    int m = (lo + hi) >> 1;
    if (a[m] < key) lo = m + 1; else hi = m;
  }
  return lo;
}

__global__ __launch_bounds__(192) void k_readout(const float* __restrict__ h,
    const int* __restrict__ gid, float* __restrict__ out) {
  int g = blockIdx.x;
  int lo = lbound(gid, g), hi = lbound(gid, g + 1);
  int c = threadIdx.x;
  if (c >= HD) return;
  float s = 0.f;
  for (int r = lo; r < hi; ++r) s += h[(size_t)r * SP + c];
  out[g * HD + c] = s / fmaxf((float)(hi - lo), 1.f);
}

extern "C" void kernel_launch(void* const* d_in, const int* in_sizes, int n_in,
                              void* d_out, int out_size, void* d_ws, size_t ws_size,
                              hipStream_t stream) {
  const float* X     = (const float*)d_in[0];
  const float* snorm = (const float*)d_in[1];
  const float* W_e   = (const float*)d_in[2];
  const float* b_e   = (const float*)d_in[3];
  const float* Wl[3]  = {(const float*)d_in[4], (const float*)d_in[8],  (const float*)d_in[12]};
  const float* bl[3]  = {(const float*)d_in[5], (const float*)d_in[9],  (const float*)d_in[13]};
  const float* gl[3]  = {(const float*)d_in[6], (const float*)d_in[10], (const float*)d_in[14]};
  const float* btl[3] = {(const float*)d_in[7], (const float*)d_in[11], (const float*)d_in[15]};
  const int* src = (const int*)d_in[16];
  const int* dst = (const int*)d_in[17];
  const int* gid = (const int*)d_in[18];
  float* out = (float*)d_out;

  char* p = (char*)d_ws;
  float* h   = (float*)p; p += sizeof(float) * (size_t)NN * SP;          // 59.2 MB
  f16* aggt  = (f16*)p;   p += sizeof(f16) * (size_t)NRB * 20 * 128;     // 32 MB (A-tiles; h2 aliases; Xt aliases)
  f16* hh    = (f16*)p;   p += sizeof(f16) * (size_t)NN * HD;            // 29.2 MB
  f16* Wt    = (f16*)p;   p += sizeof(f16) * 25600;
  float* bp  = (float*)p; p += sizeof(float) * 160;
  float* st  = (float*)p; p += sizeof(float) * 320;
  float* ns  = (float*)p; p += sizeof(float) * NN;
  float* nd  = (float*)p; p += sizeof(float) * NN;
  int* cs   = (int*)p; p += sizeof(int) * NN;
  int* cd   = (int*)p; p += sizeof(int) * NN;
  int* offs = (int*)p; p += sizeof(int) * (NN + 1);
  int* cur  = (int*)p; p += sizeof(int) * NN;
  int* part = (int*)p; p += sizeof(int) * 512;
  int* csr  = (int*)p; p += sizeof(int) * NE;

  f16* Xt = aggt;              // alias: Xt (12.8 MB) lives only during embed
  f16* h2 = aggt;              // alias: layer GEMM writes h2 in-place over its A rows

  hipMemsetAsync(cs, 0, sizeof(int) * 2 * (size_t)NN, stream);

  k_hist <<<(NE + 255) / 256, 256, 0, stream>>>(src, dst, cs, cd);
  k_norms<<<NSB, 256, 0, stream>>>(cs, cd, ns, nd);
  k_scan1<<<NSB, 256, 0, stream>>>(cd, offs, part);
  k_scan2<<<1, 512, 0, stream>>>(part);
  k_scan3<<<NSB, 256, 0, stream>>>(offs, part, cur);
  k_fill <<<(NE + 255) / 256, 256, 0, stream>>>(src, dst, cur, csr);

  const int GB = (NRB + 7) / 8;   // 782 MFMA blocks

  // embed: h = X @ W_e + b_e  (KG=8, 2 k-steps); also produce hh
  k_convX<<<(NRB * 8 * 16 + 255) / 256, 256, 0, stream>>>(X, Xt);
  k_padWe<<<40, 256, 0, stream>>>(W_e, Wt);
  k_padb<<<1, 192, 0, stream>>>(b_e, bp);
  k_mfma<8, 2, false><<<GB, 256, 0, stream>>>(Xt, Wt, bp, nullptr, h, hh, nullptr, nullptr);

  for (int l = 0; l < 3; ++l) {
    k_pull<<<(NN * 64 + 255) / 256, 256, 0, stream>>>(hh, ns, nd, offs, csr, aggt);
    k_padW<<<100, 256, 0, stream>>>(Wl[l], Wt);
    k_padb<<<1, 192, 0, stream>>>(bl[l], bp);
    hipMemsetAsync(st, 0, sizeof(float) * 320, stream);
    k_mfma<20, 5, true><<<GB, 256, 0, stream>>>(aggt, Wt, bp, snorm, nullptr, nullptr, h2, st);
    k_update<<<1024, 192, 0, stream>>>(h2, st, gl[l], btl[l], h, hh);
  }

  k_readout<<<NG, 192, 0, stream>>>(h, gid, out);
}

// Round 5
// 812.351 us; speedup vs baseline: 4.9864x; 1.2840x over previous
//
#include <hip/hip_runtime.h>

#define NN 100000
#define NE 1000000
#define NG 256
#define HD 146
#define SP 148          // padded row stride (elements) for h (fp32) and hh (f16)
#define EPSF 1e-5f
#define NSB 391         // ceil(NN/256)
#define NRB 6250        // NN/16 row-blocks (exact)

typedef _Float16 f16;
typedef f16 f16x8 __attribute__((ext_vector_type(8)));
typedef f16 f16x4 __attribute__((ext_vector_type(4)));
typedef float f32x4 __attribute__((ext_vector_type(4)));

// ---------------- degree histograms ----------------
__global__ void k_hist(const int* __restrict__ src, const int* __restrict__ dst,
                       int* __restrict__ cs, int* __restrict__ cd) {
  int e = blockIdx.x * 256 + threadIdx.x;
  if (e < NE) {
    atomicAdd(&cs[src[e]], 1);
    atomicAdd(&cd[dst[e]], 1);
  }
}

__global__ void k_norms(const int* __restrict__ cs, const int* __restrict__ cd,
                        float* __restrict__ ns, float* __restrict__ nd) {
  int i = blockIdx.x * 256 + threadIdx.x;
  if (i < NN) {
    ns[i] = rsqrtf(fmaxf((float)cs[i], 1.f));
    nd[i] = rsqrtf(fmaxf((float)cd[i], 1.f));
  }
}

// ---------------- exclusive scan of cd -> offs ----------------
__global__ void k_scan1(const int* __restrict__ cnt, int* __restrict__ offs,
                        int* __restrict__ part) {
  __shared__ int sm[256];
  int t = threadIdx.x, i = blockIdx.x * 256 + t;
  int v = (i < NN) ? cnt[i] : 0;
  sm[t] = v; __syncthreads();
  for (int o = 1; o < 256; o <<= 1) {
    int a = (t >= o) ? sm[t - o] : 0;
    __syncthreads();
    sm[t] += a;
    __syncthreads();
  }
  if (i < NN) offs[i] = sm[t] - v;
  if (t == 255) part[blockIdx.x] = sm[255];
}

__global__ void k_scan2(int* __restrict__ part) {
  __shared__ int sm[512];
  int t = threadIdx.x;
  int v = (t < NSB) ? part[t] : 0;
  sm[t] = v; __syncthreads();
  for (int o = 1; o < 512; o <<= 1) {
    int a = (t >= o) ? sm[t - o] : 0;
    __syncthreads();
    sm[t] += a;
    __syncthreads();
  }
  if (t < NSB) part[t] = sm[t] - v;
}

__global__ void k_scan3(int* __restrict__ offs, const int* __restrict__ part,
                        int* __restrict__ cur) {
  int i = blockIdx.x * 256 + threadIdx.x;
  if (i < NN) {
    int o = offs[i] + part[blockIdx.x];
    offs[i] = o;
    cur[i] = o;
  }
  if (i == 0) offs[NN] = NE;
}

__global__ void k_fill(const int* __restrict__ src, const int* __restrict__ dst,
                       int* __restrict__ cur, int* __restrict__ csr) {
  int e = blockIdx.x * 256 + threadIdx.x;
  if (e < NE) {
    int d = dst[e];
    int p = atomicAdd(&cur[d], 1);
    csr[p] = src[e];
  }
}

// ---------------- pull: pipelined gather, wave per node ----------------
// hh: f16 [NN][SP]; aggt: tiled f16 [NRB][20 kg][16 pos][8]
__device__ __forceinline__ float rl_f(float v, int idx) {
  return __int_as_float(__builtin_amdgcn_readlane(__float_as_int(v), idx));
}

__global__ __launch_bounds__(256) void k_pull(const f16* __restrict__ hh,
    const float* __restrict__ ns, const float* __restrict__ nd,
    const int* __restrict__ offs, const int* __restrict__ csr,
    f16* __restrict__ aggt) {
  int wid = (blockIdx.x * 256 + threadIdx.x) >> 6;
  int lane = threadIdx.x & 63;
  if (wid >= NN) return;
  int lo = offs[wid], hi = offs[wid + 1];
  f32x4 acc = (f32x4)0.f;
  const f16* hcol = hh + 4 * lane;   // lane covers cols 4L..4L+3 (L<37)

  for (int b0 = lo; b0 < hi; b0 += 64) {
    int cnt = min(64, hi - b0);
    int sv = 0; float nv = 0.f;
    if (lane < cnt) { sv = csr[b0 + lane]; nv = ns[sv]; }   // 1 coalesced + 1 gather per 64 edges
    if (lane < 37) {
      int g = 0;
      for (; g + 8 <= cnt; g += 8) {          // 8 independent row loads in flight
        int s[8]; float w[8]; f16x4 r[8];
#pragma unroll
        for (int j = 0; j < 8; ++j) {
          s[j] = __builtin_amdgcn_readlane(sv, g + j);
          w[j] = rl_f(nv, g + j);
        }
#pragma unroll
        for (int j = 0; j < 8; ++j) r[j] = *(const f16x4*)(hcol + (size_t)s[j] * SP);
#pragma unroll
        for (int j = 0; j < 8; ++j) {
          acc[0] = fmaf(w[j], (float)r[j][0], acc[0]);
          acc[1] = fmaf(w[j], (float)r[j][1], acc[1]);
          acc[2] = fmaf(w[j], (float)r[j][2], acc[2]);
          acc[3] = fmaf(w[j], (float)r[j][3], acc[3]);
        }
      }
      for (; g < cnt; g += 4) {               // clamped 4-wide tail (dup loads = cache hits)
        int s[4]; float w[4]; f16x4 r[4];
#pragma unroll
        for (int j = 0; j < 4; ++j) {
          int e = g + j;
          int ec = (e < cnt) ? e : (cnt - 1);
          s[j] = __builtin_amdgcn_readlane(sv, ec);
          float ww = rl_f(nv, ec);
          w[j] = (e < cnt) ? ww : 0.f;
        }
#pragma unroll
        for (int j = 0; j < 4; ++j) r[j] = *(const f16x4*)(hcol + (size_t)s[j] * SP);
#pragma unroll
        for (int j = 0; j < 4; ++j) {
          acc[0] = fmaf(w[j], (float)r[j][0], acc[0]);
          acc[1] = fmaf(w[j], (float)r[j][1], acc[1]);
          acc[2] = fmaf(w[j], (float)r[j][2], acc[2]);
          acc[3] = fmaf(w[j], (float)r[j][3], acc[3]);
        }
      }
    }
  }

  if (lane < 40) {                     // lanes 37..39 zero-fill cols 148..159 (MFMA K-pad)
    float sc = nd[wid];
    int B = wid >> 4, pos = wid & 15;
    int c = 4 * lane;
    f16x4 o = (f16x4)(f16)0;
    if (lane < 37) {
      o[0] = (f16)(acc[0] * sc);
      o[1] = (f16)(acc[1] * sc);
      o[2] = (f16)(acc[2] * sc);
      o[3] = (f16)(acc[3] * sc);
    }
    *(f16x4*)(aggt + ((size_t)(B * 20 + (c >> 3)) * 16 + pos) * 8 + (c & 7)) = o;
  }
}

// ---------------- one-shot prep: all weights/biases tiled f16 + st zero ----------------
__global__ void k_prep(const float* __restrict__ W_e, const float* __restrict__ W1,
                       const float* __restrict__ W2, const float* __restrict__ W3,
                       const float* __restrict__ b_e, const float* __restrict__ b1,
                       const float* __restrict__ b2, const float* __restrict__ b3,
                       f16* __restrict__ WtE, f16* __restrict__ Wt,
                       float* __restrict__ bp, float* __restrict__ st) {
  int idx = blockIdx.x * 256 + threadIdx.x;
  if (idx < 10240) {                       // W_e [64][146] -> [10 cb][8 kg][16][8]
    int j = idx & 7, pos = (idx >> 3) & 15;
    int rem = idx >> 7;
    int kg = rem & 7, cb = rem >> 3;
    int c = cb * 16 + pos, k = kg * 8 + j;
    WtE[idx] = (c < HD) ? (f16)W_e[k * HD + c] : (f16)0;
  } else if (idx < 87040) {                // W_l [146][146] -> [10 cb][20 kg][16][8] x3
    int i2 = idx - 10240;
    int l = i2 / 25600, m = i2 % 25600;
    const float* W = (l == 0) ? W1 : (l == 1) ? W2 : W3;
    int j = m & 7, pos = (m >> 3) & 15;
    int rem = m >> 7;
    int kg = rem % 20, cb = rem / 20;
    int c = cb * 16 + pos, k = kg * 8 + j;
    Wt[i2] = (k < HD && c < HD) ? (f16)W[k * HD + c] : (f16)0;
  } else if (idx < 87680) {                // biases padded to 160, x4
    int i2 = idx - 87040;
    int which = i2 / 160, t = i2 % 160;
    const float* b = (which == 0) ? b_e : (which == 1) ? b1 : (which == 2) ? b2 : b3;
    bp[i2] = (t < HD) ? b[t] : 0.f;
  } else if (idx < 88640) {                // BN stat accumulators, 3 x 320
    st[idx - 87680] = 0.f;
  }
}

// X fp32 [NN][64] -> Xt tiled [NRB][8 kg][16 pos][8 j]
__global__ void k_convX(const float* __restrict__ X, f16* __restrict__ Xt) {
  int i = blockIdx.x * 256 + threadIdx.x;
  if (i >= NRB * 8 * 16) return;
  int pos = i & 15, kg = (i >> 4) & 7, RB = i >> 7;
  const float* src = X + ((size_t)RB * 16 + pos) * 64 + kg * 8;
  f16x8 v;
#pragma unroll
  for (int j = 0; j < 8; ++j) v[j] = (f16)src[j];
  *(f16x8*)(Xt + (size_t)i * 8) = v;
}

// ---------------- MFMA GEMM ----------------
// A tiled [NRB][KG][16][8], W tiled [10][KG][16][8]; BM=128, BN=160, 4 waves (2x2).
// LAYER: out h2 f16 row-major [NN][160] (+bias,*snorm, fused BN stats)
// !LAYER: out h fp32 [NN][SP] cols<146 (+bias) and hh f16 [NN][SP] (zeros in pad cols)
template<int KG, int NSTEP, bool LAYER>
__global__ __launch_bounds__(256) void k_mfma(
    const f16* __restrict__ At, const f16* __restrict__ Wt,
    const float* __restrict__ bp, const float* __restrict__ snorm,
    float* __restrict__ Cf, f16* __restrict__ Hh,
    f16* __restrict__ Ch, float* __restrict__ st) {
  __shared__ __align__(16) f16 As[8 * 512];
  __shared__ __align__(16) f16 Ws[10 * 512];
  __shared__ float bsum[160], bsq[160];

  int t = threadIdx.x;
  int w = t >> 6, l = t & 63;
  int wr = w >> 1, wc = w & 1;
  int l15 = l & 15, l4 = l >> 4;
  int RB0 = blockIdx.x * 8;

  if (LAYER && t < 160) { bsum[t] = 0.f; bsq[t] = 0.f; }

  f32x4 acc[4][5];
#pragma unroll
  for (int i = 0; i < 4; ++i)
#pragma unroll
    for (int j = 0; j < 5; ++j) acc[i][j] = (f32x4)0.f;

#pragma unroll 1
  for (int s = 0; s < NSTEP; ++s) {
    __syncthreads();
#pragma unroll
    for (int u = 0; u < 2; ++u) {
      int i = t + u * 256;
      int rb = i >> 6, p = i & 63;
      int RB = RB0 + rb;
      f16x8 v = (f16x8)(f16)0;
      if (RB < NRB) v = *(const f16x8*)(At + ((size_t)RB * KG + 4 * s) * 128 + p * 8);
      *(f16x8*)(As + rb * 512 + p * 8) = v;
    }
#pragma unroll
    for (int u = 0; u < 3; ++u) {
      int m = t + u * 256;
      if (m < 640) {
        int cb = m >> 6, p = m & 63;
        f16x8 v = *(const f16x8*)(Wt + ((size_t)cb * KG + 4 * s) * 128 + p * 8);
        *(f16x8*)(Ws + cb * 512 + p * 8) = v;
      }
    }
    __syncthreads();

    f16x8 af[4], bf[5];
#pragma unroll
    for (int i = 0; i < 4; ++i)
      af[i] = *(const f16x8*)(As + (wr * 4 + i) * 512 + l4 * 128 + l15 * 8);
#pragma unroll
    for (int j = 0; j < 5; ++j)
      bf[j] = *(const f16x8*)(Ws + (wc * 5 + j) * 512 + l4 * 128 + l15 * 8);
#pragma unroll
    for (int i = 0; i < 4; ++i)
#pragma unroll
      for (int j = 0; j < 5; ++j)
        acc[i][j] = __builtin_amdgcn_mfma_f32_16x16x32_f16(af[i], bf[j], acc[i][j], 0, 0, 0);
  }

  float cs[5], cq[5];
#pragma unroll
  for (int j = 0; j < 5; ++j) { cs[j] = 0.f; cq[j] = 0.f; }

  int colbase = wc * 80;
  int rowbase = RB0 * 16 + wr * 64;
#pragma unroll
  for (int i = 0; i < 4; ++i) {
#pragma unroll
    for (int r = 0; r < 4; ++r) {
      int row = rowbase + i * 16 + l4 * 4 + r;
      bool ok = row < NN;
      float sn = 1.f;
      if (LAYER && ok) sn = snorm[row];
#pragma unroll
      for (int j = 0; j < 5; ++j) {
        int col = colbase + j * 16 + l15;
        float v = acc[i][j][r] + bp[col];
        if (LAYER) {
          v *= sn;
          if (ok) {
            Ch[(size_t)row * 160 + col] = (f16)v;
            cs[j] += v;
            cq[j] = fmaf(v, v, cq[j]);
          }
        } else {
          if (ok) {
            if (col < HD) {
              Cf[(size_t)row * SP + col] = v;
              Hh[(size_t)row * SP + col] = (f16)v;
            } else if (col < SP) {
              Hh[(size_t)row * SP + col] = (f16)0;   // zero hh pad (NaN guard)
            }
          }
        }
      }
    }
  }
  if (LAYER) {
#pragma unroll
    for (int j = 0; j < 5; ++j) {
      int col = colbase + j * 16 + l15;
      atomicAdd(&bsum[col], cs[j]);
      atomicAdd(&bsq[col], cq[j]);
    }
    __syncthreads();
    if (t < 160) {
      atomicAdd(&st[t], bsum[t]);
      atomicAdd(&st[160 + t], bsq[t]);
    }
  }
}

// ---------------- update: h += relu(bn(h2)); hh = half(h) ----------------
__global__ __launch_bounds__(192) void k_update(const f16* __restrict__ h2,
    const float* __restrict__ st, const float* __restrict__ g,
    const float* __restrict__ bt, float* __restrict__ h, f16* __restrict__ hh) {
  int c = threadIdx.x;
  if (c >= HD) return;
  float m = st[c] * (1.f / NN);
  float q = st[160 + c] * (1.f / NN);
  float iv = rsqrtf(q - m * m + EPSF);
  float a = iv * g[c];
  float b2 = bt[c] - m * a;
  for (int r = blockIdx.x; r < NN; r += gridDim.x) {
    float v = fmaf((float)h2[(size_t)r * 160 + c], a, b2);
    float hn = h[(size_t)r * SP + c] + fmaxf(v, 0.f);
    h[(size_t)r * SP + c] = hn;
    hh[(size_t)r * SP + c] = (f16)hn;
  }
}

// ---------------- readout ----------------
__device__ inline int lbound(const int* __restrict__ a, int key) {
  int lo = 0, hi = NN;
  while (lo < hi) {
    int m = (lo + hi) >> 1;
    if (a[m] < key) lo = m + 1; else hi = m;
  }
  return lo;
}

__global__ __launch_bounds__(192) void k_readout(const float* __restrict__ h,
    const int* __restrict__ gid, float* __restrict__ out) {
  int g = blockIdx.x;
  int lo = lbound(gid, g), hi = lbound(gid, g + 1);
  int c = threadIdx.x;
  if (c >= HD) return;
  float s = 0.f;
  for (int r = lo; r < hi; ++r) s += h[(size_t)r * SP + c];
  out[g * HD + c] = s / fmaxf((float)(hi - lo), 1.f);
}

extern "C" void kernel_launch(void* const* d_in, const int* in_sizes, int n_in,
                              void* d_out, int out_size, void* d_ws, size_t ws_size,
                              hipStream_t stream) {
  const float* X     = (const float*)d_in[0];
  const float* snorm = (const float*)d_in[1];
  const float* W_e   = (const float*)d_in[2];
  const float* b_e   = (const float*)d_in[3];
  const float* Wl[3]  = {(const float*)d_in[4], (const float*)d_in[8],  (const float*)d_in[12]};
  const float* bl[3]  = {(const float*)d_in[5], (const float*)d_in[9],  (const float*)d_in[13]};
  const float* gl[3]  = {(const float*)d_in[6], (const float*)d_in[10], (const float*)d_in[14]};
  const float* btl[3] = {(const float*)d_in[7], (const float*)d_in[11], (const float*)d_in[15]};
  const int* src = (const int*)d_in[16];
  const int* dst = (const int*)d_in[17];
  const int* gid = (const int*)d_in[18];
  float* out = (float*)d_out;

  char* p = (char*)d_ws;
  float* h   = (float*)p; p += sizeof(float) * (size_t)NN * SP;          // 59.2 MB
  f16* aggt  = (f16*)p;   p += sizeof(f16) * (size_t)NRB * 20 * 128;     // 32 MB (Xt & h2 alias)
  f16* hh    = (f16*)p;   p += sizeof(f16) * (size_t)NN * SP;            // 29.6 MB
  f16* WtE   = (f16*)p;   p += sizeof(f16) * 10240;
  f16* Wt    = (f16*)p;   p += sizeof(f16) * 3 * 25600;
  float* bp  = (float*)p; p += sizeof(float) * 4 * 160;
  float* st  = (float*)p; p += sizeof(float) * 3 * 320;
  float* ns  = (float*)p; p += sizeof(float) * NN;
  float* nd  = (float*)p; p += sizeof(float) * NN;
  int* cs   = (int*)p; p += sizeof(int) * NN;
  int* cd   = (int*)p; p += sizeof(int) * NN;
  int* offs = (int*)p; p += sizeof(int) * (NN + 1);
  int* cur  = (int*)p; p += sizeof(int) * NN;
  int* part = (int*)p; p += sizeof(int) * 512;
  int* csr  = (int*)p; p += sizeof(int) * NE;

  f16* Xt = aggt;
  f16* h2 = aggt;

  hipMemsetAsync(cs, 0, sizeof(int) * 2 * (size_t)NN, stream);

  k_hist <<<(NE + 255) / 256, 256, 0, stream>>>(src, dst, cs, cd);
  k_norms<<<NSB, 256, 0, stream>>>(cs, cd, ns, nd);
  k_scan1<<<NSB, 256, 0, stream>>>(cd, offs, part);
  k_scan2<<<1, 512, 0, stream>>>(part);
  k_scan3<<<NSB, 256, 0, stream>>>(offs, part, cur);
  k_fill <<<(NE + 255) / 256, 256, 0, stream>>>(src, dst, cur, csr);

  k_prep<<<347, 256, 0, stream>>>(W_e, Wl[0], Wl[1], Wl[2], b_e, bl[0], bl[1], bl[2],
                                  WtE, Wt, bp, st);

  const int GB = (NRB + 7) / 8;   // 782 MFMA blocks

  k_convX<<<(NRB * 8 * 16 + 255) / 256, 256, 0, stream>>>(X, Xt);
  k_mfma<8, 2, false><<<GB, 256, 0, stream>>>(Xt, WtE, bp, nullptr, h, hh, nullptr, nullptr);

  for (int l = 0; l < 3; ++l) {
    k_pull<<<(NN * 64 + 255) / 256, 256, 0, stream>>>(hh, ns, nd, offs, csr, aggt);
    k_mfma<20, 5, true><<<GB, 256, 0, stream>>>(aggt, Wt + l * 25600, bp + (l + 1) * 160,
                                                snorm, nullptr, nullptr, h2, st + l * 320);
    k_update<<<1024, 192, 0, stream>>>(h2, st + l * 320, gl[l], btl[l], h, hh);
  }

  k_readout<<<NG, 192, 0, stream>>>(h, gid, out);
}

// Round 6
// 697.366 us; speedup vs baseline: 5.8086x; 1.1649x over previous
//
#include <hip/hip_runtime.h>

#define NN 100000
#define NE 1000000
#define NG 256
#define HD 146
#define SP 148          // padded row stride (elements) for h (fp32) and hh (f16)
#define EPSF 1e-5f
#define NSB 391         // ceil(NN/256)
#define NRB 6250        // NN/16 row-blocks (exact)

typedef _Float16 f16;
typedef f16 f16x8 __attribute__((ext_vector_type(8)));
typedef f16 f16x4 __attribute__((ext_vector_type(4)));
typedef float f32x4 __attribute__((ext_vector_type(4)));

// ---------------- degree histograms ----------------
__global__ void k_hist(const int* __restrict__ src, const int* __restrict__ dst,
                       int* __restrict__ cs, int* __restrict__ cd) {
  int e = blockIdx.x * 256 + threadIdx.x;
  if (e < NE) {
    atomicAdd(&cs[src[e]], 1);
    atomicAdd(&cd[dst[e]], 1);
  }
}

__global__ void k_norms(const int* __restrict__ cs, const int* __restrict__ cd,
                        float* __restrict__ ns, float* __restrict__ nd) {
  int i = blockIdx.x * 256 + threadIdx.x;
  if (i < NN) {
    ns[i] = rsqrtf(fmaxf((float)cs[i], 1.f));
    nd[i] = rsqrtf(fmaxf((float)cd[i], 1.f));
  }
}

// ---------------- exclusive scan of cd -> offs ----------------
__global__ void k_scan1(const int* __restrict__ cnt, int* __restrict__ offs,
                        int* __restrict__ part) {
  __shared__ int sm[256];
  int t = threadIdx.x, i = blockIdx.x * 256 + t;
  int v = (i < NN) ? cnt[i] : 0;
  sm[t] = v; __syncthreads();
  for (int o = 1; o < 256; o <<= 1) {
    int a = (t >= o) ? sm[t - o] : 0;
    __syncthreads();
    sm[t] += a;
    __syncthreads();
  }
  if (i < NN) offs[i] = sm[t] - v;
  if (t == 255) part[blockIdx.x] = sm[255];
}

__global__ void k_scan2(int* __restrict__ part) {
  __shared__ int sm[512];
  int t = threadIdx.x;
  int v = (t < NSB) ? part[t] : 0;
  sm[t] = v; __syncthreads();
  for (int o = 1; o < 512; o <<= 1) {
    int a = (t >= o) ? sm[t - o] : 0;
    __syncthreads();
    sm[t] += a;
    __syncthreads();
  }
  if (t < NSB) part[t] = sm[t] - v;
}

__global__ void k_scan3(int* __restrict__ offs, const int* __restrict__ part,
                        int* __restrict__ cur) {
  int i = blockIdx.x * 256 + threadIdx.x;
  if (i < NN) {
    int o = offs[i] + part[blockIdx.x];
    offs[i] = o;
    cur[i] = o;
  }
  if (i == 0) offs[NN] = NE;
}

__global__ void k_fill(const int* __restrict__ src, const int* __restrict__ dst,
                       int* __restrict__ cur, int* __restrict__ csr) {
  int e = blockIdx.x * 256 + threadIdx.x;
  if (e < NE) {
    int d = dst[e];
    int p = atomicAdd(&cur[d], 1);
    csr[p] = src[e];
  }
}

// ---------------- pull: pipelined gather, wave per node ----------------
__device__ __forceinline__ float rl_f(float v, int idx) {
  return __int_as_float(__builtin_amdgcn_readlane(__float_as_int(v), idx));
}

__global__ __launch_bounds__(256) void k_pull(const f16* __restrict__ hh,
    const float* __restrict__ ns, const float* __restrict__ nd,
    const int* __restrict__ offs, const int* __restrict__ csr,
    f16* __restrict__ aggt) {
  int wid = (blockIdx.x * 256 + threadIdx.x) >> 6;
  int lane = threadIdx.x & 63;
  if (wid >= NN) return;
  int lo = offs[wid], hi = offs[wid + 1];
  f32x4 acc = (f32x4)0.f;
  const f16* hcol = hh + 4 * lane;

  for (int b0 = lo; b0 < hi; b0 += 64) {
    int cnt = min(64, hi - b0);
    int sv = 0; float nv = 0.f;
    if (lane < cnt) { sv = csr[b0 + lane]; nv = ns[sv]; }
    if (lane < 37) {
      int g = 0;
      for (; g + 8 <= cnt; g += 8) {
        int s[8]; float w[8]; f16x4 r[8];
#pragma unroll
        for (int j = 0; j < 8; ++j) {
          s[j] = __builtin_amdgcn_readlane(sv, g + j);
          w[j] = rl_f(nv, g + j);
        }
#pragma unroll
        for (int j = 0; j < 8; ++j) r[j] = *(const f16x4*)(hcol + (size_t)s[j] * SP);
#pragma unroll
        for (int j = 0; j < 8; ++j) {
          acc[0] = fmaf(w[j], (float)r[j][0], acc[0]);
          acc[1] = fmaf(w[j], (float)r[j][1], acc[1]);
          acc[2] = fmaf(w[j], (float)r[j][2], acc[2]);
          acc[3] = fmaf(w[j], (float)r[j][3], acc[3]);
        }
      }
      for (; g < cnt; g += 4) {
        int s[4]; float w[4]; f16x4 r[4];
#pragma unroll
        for (int j = 0; j < 4; ++j) {
          int e = g + j;
          int ec = (e < cnt) ? e : (cnt - 1);
          s[j] = __builtin_amdgcn_readlane(sv, ec);
          float ww = rl_f(nv, ec);
          w[j] = (e < cnt) ? ww : 0.f;
        }
#pragma unroll
        for (int j = 0; j < 4; ++j) r[j] = *(const f16x4*)(hcol + (size_t)s[j] * SP);
#pragma unroll
        for (int j = 0; j < 4; ++j) {
          acc[0] = fmaf(w[j], (float)r[j][0], acc[0]);
          acc[1] = fmaf(w[j], (float)r[j][1], acc[1]);
          acc[2] = fmaf(w[j], (float)r[j][2], acc[2]);
          acc[3] = fmaf(w[j], (float)r[j][3], acc[3]);
        }
      }
    }
  }

  if (lane < 40) {
    float sc = nd[wid];
    int B = wid >> 4, pos = wid & 15;
    int c = 4 * lane;
    f16x4 o = (f16x4)(f16)0;
    if (lane < 37) {
      o[0] = (f16)(acc[0] * sc);
      o[1] = (f16)(acc[1] * sc);
      o[2] = (f16)(acc[2] * sc);
      o[3] = (f16)(acc[3] * sc);
    }
    *(f16x4*)(aggt + ((size_t)(B * 20 + (c >> 3)) * 16 + pos) * 8 + (c & 7)) = o;
  }
}

// ---------------- one-shot prep ----------------
__global__ void k_prep(const float* __restrict__ W_e, const float* __restrict__ W1,
                       const float* __restrict__ W2, const float* __restrict__ W3,
                       const float* __restrict__ b_e, const float* __restrict__ b1,
                       const float* __restrict__ b2, const float* __restrict__ b3,
                       f16* __restrict__ WtE, f16* __restrict__ Wt,
                       float* __restrict__ bp, float* __restrict__ st) {
  int idx = blockIdx.x * 256 + threadIdx.x;
  if (idx < 10240) {
    int j = idx & 7, pos = (idx >> 3) & 15;
    int rem = idx >> 7;
    int kg = rem & 7, cb = rem >> 3;
    int c = cb * 16 + pos, k = kg * 8 + j;
    WtE[idx] = (c < HD) ? (f16)W_e[k * HD + c] : (f16)0;
  } else if (idx < 87040) {
    int i2 = idx - 10240;
    int l = i2 / 25600, m = i2 % 25600;
    const float* W = (l == 0) ? W1 : (l == 1) ? W2 : W3;
    int j = m & 7, pos = (m >> 3) & 15;
    int rem = m >> 7;
    int kg = rem % 20, cb = rem / 20;
    int c = cb * 16 + pos, k = kg * 8 + j;
    Wt[i2] = (k < HD && c < HD) ? (f16)W[k * HD + c] : (f16)0;
  } else if (idx < 87680) {
    int i2 = idx - 87040;
    int which = i2 / 160, t = i2 % 160;
    const float* b = (which == 0) ? b_e : (which == 1) ? b1 : (which == 2) ? b2 : b3;
    bp[i2] = (t < HD) ? b[t] : 0.f;
  } else if (idx < 88640) {
    st[idx - 87680] = 0.f;
  }
}

// graph row bounds: gb[g] = first row with gid >= g (gid sorted); gb[NG]=NN
__global__ void k_gbounds(const int* __restrict__ gid, int* __restrict__ gb) {
  int g = threadIdx.x;   // 0..256
  if (g > NG) return;
  int lo = 0, hi = NN;
  while (lo < hi) {
    int m = (lo + hi) >> 1;
    if (gid[m] < g) lo = m + 1; else hi = m;
  }
  gb[g] = lo;
}

// X fp32 [NN][64] -> Xt tiled [NRB][8 kg][16 pos][8 j]
__global__ void k_convX(const float* __restrict__ X, f16* __restrict__ Xt) {
  int i = blockIdx.x * 256 + threadIdx.x;
  if (i >= NRB * 8 * 16) return;
  int pos = i & 15, kg = (i >> 4) & 7, RB = i >> 7;
  const float* src = X + ((size_t)RB * 16 + pos) * 64 + kg * 8;
  f16x8 v;
#pragma unroll
  for (int j = 0; j < 8; ++j) v[j] = (f16)src[j];
  *(f16x8*)(Xt + (size_t)i * 8) = v;
}

// ---------------- MFMA GEMM ----------------
template<int KG, int NSTEP, bool LAYER>
__global__ __launch_bounds__(256) void k_mfma(
    const f16* __restrict__ At, const f16* __restrict__ Wt,
    const float* __restrict__ bp, const float* __restrict__ snorm,
    float* __restrict__ Cf, f16* __restrict__ Hh,
    f16* __restrict__ Ch, float* __restrict__ st) {
  __shared__ __align__(16) f16 As[8 * 512];
  __shared__ __align__(16) f16 Ws[10 * 512];
  __shared__ float bsum[160], bsq[160];

  int t = threadIdx.x;
  int w = t >> 6, l = t & 63;
  int wr = w >> 1, wc = w & 1;
  int l15 = l & 15, l4 = l >> 4;
  int RB0 = blockIdx.x * 8;

  if (LAYER && t < 160) { bsum[t] = 0.f; bsq[t] = 0.f; }

  f32x4 acc[4][5];
#pragma unroll
  for (int i = 0; i < 4; ++i)
#pragma unroll
    for (int j = 0; j < 5; ++j) acc[i][j] = (f32x4)0.f;

#pragma unroll 1
  for (int s = 0; s < NSTEP; ++s) {
    __syncthreads();
#pragma unroll
    for (int u = 0; u < 2; ++u) {
      int i = t + u * 256;
      int rb = i >> 6, p = i & 63;
      int RB = RB0 + rb;
      f16x8 v = (f16x8)(f16)0;
      if (RB < NRB) v = *(const f16x8*)(At + ((size_t)RB * KG + 4 * s) * 128 + p * 8);
      *(f16x8*)(As + rb * 512 + p * 8) = v;
    }
#pragma unroll
    for (int u = 0; u < 3; ++u) {
      int m = t + u * 256;
      if (m < 640) {
        int cb = m >> 6, p = m & 63;
        f16x8 v = *(const f16x8*)(Wt + ((size_t)cb * KG + 4 * s) * 128 + p * 8);
        *(f16x8*)(Ws + cb * 512 + p * 8) = v;
      }
    }
    __syncthreads();

    f16x8 af[4], bf[5];
#pragma unroll
    for (int i = 0; i < 4; ++i)
      af[i] = *(const f16x8*)(As + (wr * 4 + i) * 512 + l4 * 128 + l15 * 8);
#pragma unroll
    for (int j = 0; j < 5; ++j)
      bf[j] = *(const f16x8*)(Ws + (wc * 5 + j) * 512 + l4 * 128 + l15 * 8);
#pragma unroll
    for (int i = 0; i < 4; ++i)
#pragma unroll
      for (int j = 0; j < 5; ++j)
        acc[i][j] = __builtin_amdgcn_mfma_f32_16x16x32_f16(af[i], bf[j], acc[i][j], 0, 0, 0);
  }

  float cs[5], cq[5];
#pragma unroll
  for (int j = 0; j < 5; ++j) { cs[j] = 0.f; cq[j] = 0.f; }

  int colbase = wc * 80;
  int rowbase = RB0 * 16 + wr * 64;
#pragma unroll
  for (int i = 0; i < 4; ++i) {
#pragma unroll
    for (int r = 0; r < 4; ++r) {
      int row = rowbase + i * 16 + l4 * 4 + r;
      bool ok = row < NN;
      float sn = 1.f;
      if (LAYER && ok) sn = snorm[row];
#pragma unroll
      for (int j = 0; j < 5; ++j) {
        int col = colbase + j * 16 + l15;
        float v = acc[i][j][r] + bp[col];
        if (LAYER) {
          v *= sn;
          if (ok) {
            Ch[(size_t)row * 160 + col] = (f16)v;
            cs[j] += v;
            cq[j] = fmaf(v, v, cq[j]);
          }
        } else {
          if (ok) {
            if (col < HD) {
              Cf[(size_t)row * SP + col] = v;
              Hh[(size_t)row * SP + col] = (f16)v;
            } else if (col < SP) {
              Hh[(size_t)row * SP + col] = (f16)0;
            }
          }
        }
      }
    }
  }
  if (LAYER) {
#pragma unroll
    for (int j = 0; j < 5; ++j) {
      int col = colbase + j * 16 + l15;
      atomicAdd(&bsum[col], cs[j]);
      atomicAdd(&bsq[col], cq[j]);
    }
    __syncthreads();
    if (t < 160) {
      atomicAdd(&st[t], bsum[t]);
      atomicAdd(&st[160 + t], bsq[t]);
    }
  }
}

// ---------------- BN finalize: per-col scale/shift (pad cols -> 0) ----------------
__global__ void k_bnfin(const float* __restrict__ st, const float* __restrict__ g,
                        const float* __restrict__ bt, float* __restrict__ ab) {
  int c = threadIdx.x;
  if (c >= 160) return;
  float m = st[c] * (1.f / NN);
  float q = st[160 + c] * (1.f / NN);
  float iv = rsqrtf(q - m * m + EPSF);
  float gg = (c < HD) ? g[c] : 0.f;
  float bb = (c < HD) ? bt[c] : 0.f;
  float a = iv * gg;
  ab[c] = a;
  ab[160 + c] = bb - m * a;
}

// ---------------- update (vectorized): h += relu(h2*a+b2); hh = f16(h) ----------------
__global__ __launch_bounds__(256) void k_update(const f16* __restrict__ h2,
    const float* __restrict__ ab, float* __restrict__ h, f16* __restrict__ hh) {
  const int total = NN * 37;
  int stride = gridDim.x * 256;
  for (int idx = blockIdx.x * 256 + threadIdx.x; idx < total; idx += stride) {
    int r = idx / 37, g = idx - r * 37;
    int c = g * 4;
    f16x4 p = *(const f16x4*)(h2 + (size_t)r * 160 + c);
    f32x4 hv = *(const f32x4*)(h + (size_t)r * SP + c);
    f16x4 ho;
#pragma unroll
    for (int j = 0; j < 4; ++j) {
      float v = fmaf((float)p[j], ab[c + j], ab[160 + c + j]);
      float hn = hv[j] + fmaxf(v, 0.f);
      hv[j] = hn;
      ho[j] = (f16)hn;
    }
    *(f32x4*)(h + (size_t)r * SP + c) = hv;
    *(f16x4*)(hh + (size_t)r * SP + c) = ho;
  }
}

// ---------------- readout: 16 blocks/graph, wave-per-row, LDS reduce, atomics ----------------
__global__ __launch_bounds__(256) void k_readout1(const f16* __restrict__ hh,
    const int* __restrict__ gb, float* __restrict__ out) {
  int g = blockIdx.x >> 4, chunk = blockIdx.x & 15;
  int lo = gb[g], hi = gb[g + 1];
  int w = threadIdx.x >> 6, lane = threadIdx.x & 63;
  __shared__ float sacc[148];
  if (threadIdx.x < 148) sacc[threadIdx.x] = 0.f;
  __syncthreads();
  f32x4 acc = (f32x4)0.f;
  if (lane < 37) {
    for (int r = lo + chunk * 4 + w; r < hi; r += 64) {
      f16x4 v = *(const f16x4*)(hh + (size_t)r * SP + lane * 4);
      acc[0] += (float)v[0];
      acc[1] += (float)v[1];
      acc[2] += (float)v[2];
      acc[3] += (float)v[3];
    }
    atomicAdd(&sacc[lane * 4 + 0], acc[0]);
    atomicAdd(&sacc[lane * 4 + 1], acc[1]);
    atomicAdd(&sacc[lane * 4 + 2], acc[2]);
    atomicAdd(&sacc[lane * 4 + 3], acc[3]);
  }
  __syncthreads();
  if (threadIdx.x < HD) atomicAdd(&out[g * HD + threadIdx.x], sacc[threadIdx.x]);
}

__global__ void k_rdiv(const int* __restrict__ gb, float* __restrict__ out) {
  int g = blockIdx.x, c = threadIdx.x;
  if (c < HD) out[g * HD + c] /= fmaxf((float)(gb[g + 1] - gb[g]), 1.f);
}

extern "C" void kernel_launch(void* const* d_in, const int* in_sizes, int n_in,
                              void* d_out, int out_size, void* d_ws, size_t ws_size,
                              hipStream_t stream) {
  const float* X     = (const float*)d_in[0];
  const float* snorm = (const float*)d_in[1];
  const float* W_e   = (const float*)d_in[2];
  const float* b_e   = (const float*)d_in[3];
  const float* Wl[3]  = {(const float*)d_in[4], (const float*)d_in[8],  (const float*)d_in[12]};
  const float* bl[3]  = {(const float*)d_in[5], (const float*)d_in[9],  (const float*)d_in[13]};
  const float* gl[3]  = {(const float*)d_in[6], (const float*)d_in[10], (const float*)d_in[14]};
  const float* btl[3] = {(const float*)d_in[7], (const float*)d_in[11], (const float*)d_in[15]};
  const int* src = (const int*)d_in[16];
  const int* dst = (const int*)d_in[17];
  const int* gid = (const int*)d_in[18];
  float* out = (float*)d_out;

  char* p = (char*)d_ws;
  float* h   = (float*)p; p += sizeof(float) * (size_t)NN * SP;
  f16* aggt  = (f16*)p;   p += sizeof(f16) * (size_t)NRB * 20 * 128;
  f16* hh    = (f16*)p;   p += sizeof(f16) * (size_t)NN * SP;
  f16* WtE   = (f16*)p;   p += sizeof(f16) * 10240;
  f16* Wt    = (f16*)p;   p += sizeof(f16) * 3 * 25600;
  float* bp  = (float*)p; p += sizeof(float) * 4 * 160;
  float* st  = (float*)p; p += sizeof(float) * 3 * 320;
  float* ab  = (float*)p; p += sizeof(float) * 320;
  float* ns  = (float*)p; p += sizeof(float) * NN;
  float* nd  = (float*)p; p += sizeof(float) * NN;
  int* cs   = (int*)p; p += sizeof(int) * NN;
  int* cd   = (int*)p; p += sizeof(int) * NN;
  int* offs = (int*)p; p += sizeof(int) * (NN + 1);
  int* cur  = (int*)p; p += sizeof(int) * NN;
  int* part = (int*)p; p += sizeof(int) * 512;
  int* gb   = (int*)p; p += sizeof(int) * (NG + 1);
  int* csr  = (int*)p; p += sizeof(int) * NE;

  f16* Xt = aggt;
  f16* h2 = aggt;

  hipMemsetAsync(cs, 0, sizeof(int) * 2 * (size_t)NN, stream);
  hipMemsetAsync(out, 0, sizeof(float) * NG * HD, stream);

  k_hist <<<(NE + 255) / 256, 256, 0, stream>>>(src, dst, cs, cd);
  k_norms<<<NSB, 256, 0, stream>>>(cs, cd, ns, nd);
  k_scan1<<<NSB, 256, 0, stream>>>(cd, offs, part);
  k_scan2<<<1, 512, 0, stream>>>(part);
  k_scan3<<<NSB, 256, 0, stream>>>(offs, part, cur);
  k_fill <<<(NE + 255) / 256, 256, 0, stream>>>(src, dst, cur, csr);

  k_prep<<<347, 256, 0, stream>>>(W_e, Wl[0], Wl[1], Wl[2], b_e, bl[0], bl[1], bl[2],
                                  WtE, Wt, bp, st);
  k_gbounds<<<1, 512, 0, stream>>>(gid, gb);

  const int GB = (NRB + 7) / 8;

  k_convX<<<(NRB * 8 * 16 + 255) / 256, 256, 0, stream>>>(X, Xt);
  k_mfma<8, 2, false><<<GB, 256, 0, stream>>>(Xt, WtE, bp, nullptr, h, hh, nullptr, nullptr);

  for (int l = 0; l < 3; ++l) {
    k_pull<<<(NN * 64 + 255) / 256, 256, 0, stream>>>(hh, ns, nd, offs, csr, aggt);
    k_mfma<20, 5, true><<<GB, 256, 0, stream>>>(aggt, Wt + l * 25600, bp + (l + 1) * 160,
                                                snorm, nullptr, nullptr, h2, st + l * 320);
    k_bnfin<<<1, 192, 0, stream>>>(st + l * 320, gl[l], btl[l], ab);
    k_update<<<4096, 256, 0, stream>>>(h2, ab, h, hh);
  }

  k_readout1<<<NG * 16, 256, 0, stream>>>(hh, gb, out);
  k_rdiv<<<NG, 192, 0, stream>>>(gb, out);
}

// Round 7
// 642.607 us; speedup vs baseline: 6.3036x; 1.0852x over previous
//
#include <hip/hip_runtime.h>

#define NN 100000
#define NE 1000000
#define NG 256
#define HD 146
#define SP 148          // padded row stride (elements) for hh (f16)
#define EPSF 1e-5f
#define NSB 391         // ceil(NN/256)
#define NRB 6250        // NN/16 row-blocks (exact)

typedef _Float16 f16;
typedef f16 f16x8 __attribute__((ext_vector_type(8)));
typedef f16 f16x4 __attribute__((ext_vector_type(4)));
typedef float f32x4 __attribute__((ext_vector_type(4)));

// ---------------- in-degree histogram (cd only) ----------------
__global__ void k_hist(const int* __restrict__ dst, int* __restrict__ cd) {
  int e = blockIdx.x * 256 + threadIdx.x;
  if (e < NE) atomicAdd(&cd[dst[e]], 1);
}

__global__ void k_norms(const int* __restrict__ cs, const int* __restrict__ cd,
                        float* __restrict__ ns, float* __restrict__ nd) {
  int i = blockIdx.x * 256 + threadIdx.x;
  if (i < NN) {
    ns[i] = rsqrtf(fmaxf((float)cs[i], 1.f));
    nd[i] = rsqrtf(fmaxf((float)cd[i], 1.f));
  }
}

// ---------------- exclusive scan of cd -> offs ----------------
__global__ void k_scan1(const int* __restrict__ cnt, int* __restrict__ offs,
                        int* __restrict__ part) {
  __shared__ int sm[256];
  int t = threadIdx.x, i = blockIdx.x * 256 + t;
  int v = (i < NN) ? cnt[i] : 0;
  sm[t] = v; __syncthreads();
  for (int o = 1; o < 256; o <<= 1) {
    int a = (t >= o) ? sm[t - o] : 0;
    __syncthreads();
    sm[t] += a;
    __syncthreads();
  }
  if (i < NN) offs[i] = sm[t] - v;
  if (t == 255) part[blockIdx.x] = sm[255];
}

__global__ void k_scan2(int* __restrict__ part) {
  __shared__ int sm[512];
  int t = threadIdx.x;
  int v = (t < NSB) ? part[t] : 0;
  sm[t] = v; __syncthreads();
  for (int o = 1; o < 512; o <<= 1) {
    int a = (t >= o) ? sm[t - o] : 0;
    __syncthreads();
    sm[t] += a;
    __syncthreads();
  }
  if (t < NSB) part[t] = sm[t] - v;
}

__global__ void k_scan3(int* __restrict__ offs, const int* __restrict__ part,
                        int* __restrict__ cur) {
  int i = blockIdx.x * 256 + threadIdx.x;
  if (i < NN) {
    int o = offs[i] + part[blockIdx.x];
    offs[i] = o;
    cur[i] = o;
  }
  if (i == 0) offs[NN] = NE;
}

// fill CSR + out-degree histogram (cs) in one pass
__global__ void k_fill(const int* __restrict__ src, const int* __restrict__ dst,
                       int* __restrict__ cur, int* __restrict__ csr,
                       int* __restrict__ cs) {
  int e = blockIdx.x * 256 + threadIdx.x;
  if (e < NE) {
    int s = src[e];
    atomicAdd(&cs[s], 1);
    int p = atomicAdd(&cur[dst[e]], 1);
    csr[p] = s;
  }
}

// ---------------- pull: pipelined gather, wave per node ----------------
__device__ __forceinline__ float rl_f(float v, int idx) {
  return __int_as_float(__builtin_amdgcn_readlane(__float_as_int(v), idx));
}

__global__ __launch_bounds__(256) void k_pull(const f16* __restrict__ hh,
    const float* __restrict__ ns, const float* __restrict__ nd,
    const int* __restrict__ offs, const int* __restrict__ csr,
    f16* __restrict__ aggt) {
  int wid = (blockIdx.x * 256 + threadIdx.x) >> 6;
  int lane = threadIdx.x & 63;
  if (wid >= NN) return;
  int lo = offs[wid], hi = offs[wid + 1];
  f32x4 acc = (f32x4)0.f;
  const f16* hcol = hh + 4 * lane;

  for (int b0 = lo; b0 < hi; b0 += 64) {
    int cnt = min(64, hi - b0);
    int sv = 0; float nv = 0.f;
    if (lane < cnt) { sv = csr[b0 + lane]; nv = ns[sv]; }
    if (lane < 37) {
      int g = 0;
      for (; g + 8 <= cnt; g += 8) {
        int s[8]; float w[8]; f16x4 r[8];
#pragma unroll
        for (int j = 0; j < 8; ++j) {
          s[j] = __builtin_amdgcn_readlane(sv, g + j);
          w[j] = rl_f(nv, g + j);
        }
#pragma unroll
        for (int j = 0; j < 8; ++j) r[j] = *(const f16x4*)(hcol + (size_t)s[j] * SP);
#pragma unroll
        for (int j = 0; j < 8; ++j) {
          acc[0] = fmaf(w[j], (float)r[j][0], acc[0]);
          acc[1] = fmaf(w[j], (float)r[j][1], acc[1]);
          acc[2] = fmaf(w[j], (float)r[j][2], acc[2]);
          acc[3] = fmaf(w[j], (float)r[j][3], acc[3]);
        }
      }
      for (; g < cnt; g += 4) {
        int s[4]; float w[4]; f16x4 r[4];
#pragma unroll
        for (int j = 0; j < 4; ++j) {
          int e = g + j;
          int ec = (e < cnt) ? e : (cnt - 1);
          s[j] = __builtin_amdgcn_readlane(sv, ec);
          float ww = rl_f(nv, ec);
          w[j] = (e < cnt) ? ww : 0.f;
        }
#pragma unroll
        for (int j = 0; j < 4; ++j) r[j] = *(const f16x4*)(hcol + (size_t)s[j] * SP);
#pragma unroll
        for (int j = 0; j < 4; ++j) {
          acc[0] = fmaf(w[j], (float)r[j][0], acc[0]);
          acc[1] = fmaf(w[j], (float)r[j][1], acc[1]);
          acc[2] = fmaf(w[j], (float)r[j][2], acc[2]);
          acc[3] = fmaf(w[j], (float)r[j][3], acc[3]);
        }
      }
    }
  }

  if (lane < 40) {
    float sc = nd[wid];
    int B = wid >> 4, pos = wid & 15;
    int c = 4 * lane;
    f16x4 o = (f16x4)(f16)0;
    if (lane < 37) {
      o[0] = (f16)(acc[0] * sc);
      o[1] = (f16)(acc[1] * sc);
      o[2] = (f16)(acc[2] * sc);
      o[3] = (f16)(acc[3] * sc);
    }
    *(f16x4*)(aggt + ((size_t)(B * 20 + (c >> 3)) * 16 + pos) * 8 + (c & 7)) = o;
  }
}

// ---------------- one-shot prep ----------------
__global__ void k_prep(const float* __restrict__ W_e, const float* __restrict__ W1,
                       const float* __restrict__ W2, const float* __restrict__ W3,
                       const float* __restrict__ b_e, const float* __restrict__ b1,
                       const float* __restrict__ b2, const float* __restrict__ b3,
                       f16* __restrict__ WtE, f16* __restrict__ Wt,
                       float* __restrict__ bp, float* __restrict__ st) {
  int idx = blockIdx.x * 256 + threadIdx.x;
  if (idx < 10240) {
    int j = idx & 7, pos = (idx >> 3) & 15;
    int rem = idx >> 7;
    int kg = rem & 7, cb = rem >> 3;
    int c = cb * 16 + pos, k = kg * 8 + j;
    WtE[idx] = (c < HD) ? (f16)W_e[k * HD + c] : (f16)0;
  } else if (idx < 87040) {
    int i2 = idx - 10240;
    int l = i2 / 25600, m = i2 % 25600;
    const float* W = (l == 0) ? W1 : (l == 1) ? W2 : W3;
    int j = m & 7, pos = (m >> 3) & 15;
    int rem = m >> 7;
    int kg = rem % 20, cb = rem / 20;
    int c = cb * 16 + pos, k = kg * 8 + j;
    Wt[i2] = (k < HD && c < HD) ? (f16)W[k * HD + c] : (f16)0;
  } else if (idx < 87680) {
    int i2 = idx - 87040;
    int which = i2 / 160, t = i2 % 160;
    const float* b = (which == 0) ? b_e : (which == 1) ? b1 : (which == 2) ? b2 : b3;
    bp[i2] = (t < HD) ? b[t] : 0.f;
  } else if (idx < 88640) {
    st[idx - 87680] = 0.f;
  }
}

// graph row bounds
__global__ void k_gbounds(const int* __restrict__ gid, int* __restrict__ gb) {
  int g = threadIdx.x;
  if (g > NG) return;
  int lo = 0, hi = NN;
  while (lo < hi) {
    int m = (lo + hi) >> 1;
    if (gid[m] < g) lo = m + 1; else hi = m;
  }
  gb[g] = lo;
}

// X fp32 [NN][64] -> Xt tiled [NRB][8 kg][16 pos][8 j]
__global__ void k_convX(const float* __restrict__ X, f16* __restrict__ Xt) {
  int i = blockIdx.x * 256 + threadIdx.x;
  if (i >= NRB * 8 * 16) return;
  int pos = i & 15, kg = (i >> 4) & 7, RB = i >> 7;
  const float* src = X + ((size_t)RB * 16 + pos) * 64 + kg * 8;
  f16x8 v;
#pragma unroll
  for (int j = 0; j < 8; ++j) v[j] = (f16)src[j];
  *(f16x8*)(Xt + (size_t)i * 8) = v;
}

// ---------------- MFMA GEMM ----------------
// LAYER: out h2 f16 [NN][160] (+bias,*snorm, fused BN stats)
// !LAYER: out hh f16 [NN][SP] (+bias, zeros in pad cols)
template<int KG, int NSTEP, bool LAYER>
__global__ __launch_bounds__(256) void k_mfma(
    const f16* __restrict__ At, const f16* __restrict__ Wt,
    const float* __restrict__ bp, const float* __restrict__ snorm,
    f16* __restrict__ Hh, f16* __restrict__ Ch, float* __restrict__ st) {
  __shared__ __align__(16) f16 As[8 * 512];
  __shared__ __align__(16) f16 Ws[10 * 512];
  __shared__ float bsum[160], bsq[160];

  int t = threadIdx.x;
  int w = t >> 6, l = t & 63;
  int wr = w >> 1, wc = w & 1;
  int l15 = l & 15, l4 = l >> 4;
  int RB0 = blockIdx.x * 8;

  if (LAYER && t < 160) { bsum[t] = 0.f; bsq[t] = 0.f; }

  f32x4 acc[4][5];
#pragma unroll
  for (int i = 0; i < 4; ++i)
#pragma unroll
    for (int j = 0; j < 5; ++j) acc[i][j] = (f32x4)0.f;

#pragma unroll 1
  for (int s = 0; s < NSTEP; ++s) {
    __syncthreads();
#pragma unroll
    for (int u = 0; u < 2; ++u) {
      int i = t + u * 256;
      int rb = i >> 6, p = i & 63;
      int RB = RB0 + rb;
      f16x8 v = (f16x8)(f16)0;
      if (RB < NRB) v = *(const f16x8*)(At + ((size_t)RB * KG + 4 * s) * 128 + p * 8);
      *(f16x8*)(As + rb * 512 + p * 8) = v;
    }
#pragma unroll
    for (int u = 0; u < 3; ++u) {
      int m = t + u * 256;
      if (m < 640) {
        int cb = m >> 6, p = m & 63;
        f16x8 v = *(const f16x8*)(Wt + ((size_t)cb * KG + 4 * s) * 128 + p * 8);
        *(f16x8*)(Ws + cb * 512 + p * 8) = v;
      }
    }
    __syncthreads();

    f16x8 af[4], bf[5];
#pragma unroll
    for (int i = 0; i < 4; ++i)
      af[i] = *(const f16x8*)(As + (wr * 4 + i) * 512 + l4 * 128 + l15 * 8);
#pragma unroll
    for (int j = 0; j < 5; ++j)
      bf[j] = *(const f16x8*)(Ws + (wc * 5 + j) * 512 + l4 * 128 + l15 * 8);
#pragma unroll
    for (int i = 0; i < 4; ++i)
#pragma unroll
      for (int j = 0; j < 5; ++j)
        acc[i][j] = __builtin_amdgcn_mfma_f32_16x16x32_f16(af[i], bf[j], acc[i][j], 0, 0, 0);
  }

  float cs[5], cq[5];
#pragma unroll
  for (int j = 0; j < 5; ++j) { cs[j] = 0.f; cq[j] = 0.f; }

  int colbase = wc * 80;
  int rowbase = RB0 * 16 + wr * 64;
#pragma unroll
  for (int i = 0; i < 4; ++i) {
#pragma unroll
    for (int r = 0; r < 4; ++r) {
      int row = rowbase + i * 16 + l4 * 4 + r;
      bool ok = row < NN;
      float sn = 1.f;
      if (LAYER && ok) sn = snorm[row];
#pragma unroll
      for (int j = 0; j < 5; ++j) {
        int col = colbase + j * 16 + l15;
        float v = acc[i][j][r] + bp[col];
        if (LAYER) {
          v *= sn;
          if (ok) {
            Ch[(size_t)row * 160 + col] = (f16)v;
            cs[j] += v;
            cq[j] = fmaf(v, v, cq[j]);
          }
        } else {
          if (ok) {
            if (col < HD) Hh[(size_t)row * SP + col] = (f16)v;
            else if (col < SP) Hh[(size_t)row * SP + col] = (f16)0;
          }
        }
      }
    }
  }
  if (LAYER) {
#pragma unroll
    for (int j = 0; j < 5; ++j) {
      int col = colbase + j * 16 + l15;
      atomicAdd(&bsum[col], cs[j]);
      atomicAdd(&bsq[col], cq[j]);
    }
    __syncthreads();
    if (t < 160) {
      atomicAdd(&st[t], bsum[t]);
      atomicAdd(&st[160 + t], bsq[t]);
    }
  }
}

// ---------------- update (BN finalize fused): hh += relu(h2*a+b2) ----------------
__global__ __launch_bounds__(256) void k_update(const f16* __restrict__ h2,
    const float* __restrict__ st, const float* __restrict__ g,
    const float* __restrict__ bt, f16* __restrict__ hh) {
  __shared__ float ab[320];
  int t = threadIdx.x;
  if (t < 160) {
    float m = st[t] * (1.f / NN);
    float q = st[160 + t] * (1.f / NN);
    float iv = rsqrtf(q - m * m + EPSF);
    float gg = (t < HD) ? g[t] : 0.f;
    float bb = (t < HD) ? bt[t] : 0.f;
    float a = iv * gg;
    ab[t] = a;
    ab[160 + t] = bb - m * a;
  }
  __syncthreads();
  const int total = NN * 37;
  int stride = gridDim.x * 256;
  for (int idx = blockIdx.x * 256 + t; idx < total; idx += stride) {
    int r = idx / 37, gq = idx - r * 37;
    int c = gq * 4;
    f16x4 p = *(const f16x4*)(h2 + (size_t)r * 160 + c);
    f16x4 hv = *(const f16x4*)(hh + (size_t)r * SP + c);
    f16x4 ho;
#pragma unroll
    for (int j = 0; j < 4; ++j) {
      float v = fmaf((float)p[j], ab[c + j], ab[160 + c + j]);
      float hn = (float)hv[j] + fmaxf(v, 0.f);
      ho[j] = (f16)hn;
    }
    *(f16x4*)(hh + (size_t)r * SP + c) = ho;
  }
}

// ---------------- readout ----------------
__global__ __launch_bounds__(256) void k_readout1(const f16* __restrict__ hh,
    const int* __restrict__ gb, float* __restrict__ out) {
  int g = blockIdx.x >> 4, chunk = blockIdx.x & 15;
  int lo = gb[g], hi = gb[g + 1];
  int w = threadIdx.x >> 6, lane = threadIdx.x & 63;
  __shared__ float sacc[148];
  if (threadIdx.x < 148) sacc[threadIdx.x] = 0.f;
  __syncthreads();
  f32x4 acc = (f32x4)0.f;
  if (lane < 37) {
    for (int r = lo + chunk * 4 + w; r < hi; r += 64) {
      f16x4 v = *(const f16x4*)(hh + (size_t)r * SP + lane * 4);
      acc[0] += (float)v[0];
      acc[1] += (float)v[1];
      acc[2] += (float)v[2];
      acc[3] += (float)v[3];
    }
    atomicAdd(&sacc[lane * 4 + 0], acc[0]);
    atomicAdd(&sacc[lane * 4 + 1], acc[1]);
    atomicAdd(&sacc[lane * 4 + 2], acc[2]);
    atomicAdd(&sacc[lane * 4 + 3], acc[3]);
  }
  __syncthreads();
  if (threadIdx.x < HD) atomicAdd(&out[g * HD + threadIdx.x], sacc[threadIdx.x]);
}

__global__ void k_rdiv(const int* __restrict__ gb, float* __restrict__ out) {
  int g = blockIdx.x, c = threadIdx.x;
  if (c < HD) out[g * HD + c] /= fmaxf((float)(gb[g + 1] - gb[g]), 1.f);
}

extern "C" void kernel_launch(void* const* d_in, const int* in_sizes, int n_in,
                              void* d_out, int out_size, void* d_ws, size_t ws_size,
                              hipStream_t stream) {
  const float* X     = (const float*)d_in[0];
  const float* snorm = (const float*)d_in[1];
  const float* W_e   = (const float*)d_in[2];
  const float* b_e   = (const float*)d_in[3];
  const float* Wl[3]  = {(const float*)d_in[4], (const float*)d_in[8],  (const float*)d_in[12]};
  const float* bl[3]  = {(const float*)d_in[5], (const float*)d_in[9],  (const float*)d_in[13]};
  const float* gl[3]  = {(const float*)d_in[6], (const float*)d_in[10], (const float*)d_in[14]};
  const float* btl[3] = {(const float*)d_in[7], (const float*)d_in[11], (const float*)d_in[15]};
  const int* src = (const int*)d_in[16];
  const int* dst = (const int*)d_in[17];
  const int* gid = (const int*)d_in[18];
  float* out = (float*)d_out;

  char* p = (char*)d_ws;
  f16* hh    = (f16*)p;   p += sizeof(f16) * (size_t)NN * SP;          // 29.6 MB (residual state)
  f16* aggt  = (f16*)p;   p += sizeof(f16) * (size_t)NRB * 20 * 128;   // 32 MB (Xt & h2 alias)
  f16* WtE   = (f16*)p;   p += sizeof(f16) * 10240;
  f16* Wt    = (f16*)p;   p += sizeof(f16) * 3 * 25600;
  float* bp  = (float*)p; p += sizeof(float) * 4 * 160;
  float* st  = (float*)p; p += sizeof(float) * 3 * 320;
  float* ns  = (float*)p; p += sizeof(float) * NN;
  float* nd  = (float*)p; p += sizeof(float) * NN;
  int* cs   = (int*)p; p += sizeof(int) * NN;
  int* cd   = (int*)p; p += sizeof(int) * NN;
  int* offs = (int*)p; p += sizeof(int) * (NN + 1);
  int* cur  = (int*)p; p += sizeof(int) * NN;
  int* part = (int*)p; p += sizeof(int) * 512;
  int* gb   = (int*)p; p += sizeof(int) * (NG + 1);
  int* csr  = (int*)p; p += sizeof(int) * NE;

  f16* Xt = aggt;
  f16* h2 = aggt;

  hipMemsetAsync(cs, 0, sizeof(int) * 2 * (size_t)NN, stream);   // cs & cd contiguous
  hipMemsetAsync(out, 0, sizeof(float) * NG * HD, stream);

  k_hist <<<(NE + 255) / 256, 256, 0, stream>>>(dst, cd);
  k_scan1<<<NSB, 256, 0, stream>>>(cd, offs, part);
  k_scan2<<<1, 512, 0, stream>>>(part);
  k_scan3<<<NSB, 256, 0, stream>>>(offs, part, cur);
  k_fill <<<(NE + 255) / 256, 256, 0, stream>>>(src, dst, cur, csr, cs);
  k_norms<<<NSB, 256, 0, stream>>>(cs, cd, ns, nd);

  k_prep<<<347, 256, 0, stream>>>(W_e, Wl[0], Wl[1], Wl[2], b_e, bl[0], bl[1], bl[2],
                                  WtE, Wt, bp, st);
  k_gbounds<<<1, 512, 0, stream>>>(gid, gb);

  const int GB = (NRB + 7) / 8;

  k_convX<<<(NRB * 8 * 16 + 255) / 256, 256, 0, stream>>>(X, Xt);
  k_mfma<8, 2, false><<<GB, 256, 0, stream>>>(Xt, WtE, bp, nullptr, hh, nullptr, nullptr);

  for (int l = 0; l < 3; ++l) {
    k_pull<<<(NN * 64 + 255) / 256, 256, 0, stream>>>(hh, ns, nd, offs, csr, aggt);
    k_mfma<20, 5, true><<<GB, 256, 0, stream>>>(aggt, Wt + l * 25600, bp + (l + 1) * 160,
                                                snorm, nullptr, h2, st + l * 320);
    k_update<<<4096, 256, 0, stream>>>(h2, st + l * 320, gl[l], btl[l], hh);
  }

  k_readout1<<<NG * 16, 256, 0, stream>>>(hh, gb, out);
  k_rdiv<<<NG, 192, 0, stream>>>(gb, out);
}

// Round 8
// 618.419 us; speedup vs baseline: 6.5501x; 1.0391x over previous
//
#include <hip/hip_runtime.h>

#define NN 100000
#define NE 1000000
#define NG 256
#define HD 146
#define SP 148          // padded row stride (elements) for hh (f16)
#define EPSF 1e-5f
#define NSB 391         // ceil(NN/256)
#define NRB 6250        // NN/16 row-blocks (exact)
#define GB 782          // MFMA grid = ceil(NRB/8)

typedef _Float16 f16;
typedef f16 f16x8 __attribute__((ext_vector_type(8)));
typedef f16 f16x4 __attribute__((ext_vector_type(4)));
typedef float f32x4 __attribute__((ext_vector_type(4)));

// ---------------- in-degree histogram into XCD-local partials ----------------
__global__ void k_hist(const int* __restrict__ dst, int* __restrict__ cd8) {
  int e = blockIdx.x * 256 + threadIdx.x;
  int q = blockIdx.x & 7;
  if (e < NE) atomicAdd(&cd8[q * NN + dst[e]], 1);
}

// reduce cd8 -> cd, nd
__global__ void k_cdred(const int* __restrict__ cd8, int* __restrict__ cd,
                        float* __restrict__ nd) {
  int i = blockIdx.x * 256 + threadIdx.x;
  if (i < NN) {
    int c = 0;
#pragma unroll
    for (int q = 0; q < 8; ++q) c += cd8[q * NN + i];
    cd[i] = c;
    nd[i] = rsqrtf(fmaxf((float)c, 1.f));
  }
}

// ---------------- exclusive scan of cd -> offs ----------------
__global__ void k_scan1(const int* __restrict__ cnt, int* __restrict__ offs,
                        int* __restrict__ part) {
  __shared__ int sm[256];
  int t = threadIdx.x, i = blockIdx.x * 256 + t;
  int v = (i < NN) ? cnt[i] : 0;
  sm[t] = v; __syncthreads();
  for (int o = 1; o < 256; o <<= 1) {
    int a = (t >= o) ? sm[t - o] : 0;
    __syncthreads();
    sm[t] += a;
    __syncthreads();
  }
  if (i < NN) offs[i] = sm[t] - v;
  if (t == 255) part[blockIdx.x] = sm[255];
}

__global__ void k_scan2(int* __restrict__ part) {
  __shared__ int sm[512];
  int t = threadIdx.x;
  int v = (t < NSB) ? part[t] : 0;
  sm[t] = v; __syncthreads();
  for (int o = 1; o < 512; o <<= 1) {
    int a = (t >= o) ? sm[t - o] : 0;
    __syncthreads();
    sm[t] += a;
    __syncthreads();
  }
  if (t < NSB) part[t] = sm[t] - v;
}

__global__ void k_scan3(int* __restrict__ offs, const int* __restrict__ part) {
  int i = blockIdx.x * 256 + threadIdx.x;
  if (i < NN) offs[i] += part[blockIdx.x];
  if (i == 0) offs[NN] = NE;
}

// per-partition CSR base offsets: cur8[q][i] = offs[i] + sum_{q'<q} cd8[q'][i]
__global__ void k_bases(const int* __restrict__ offs, const int* __restrict__ cd8,
                        int* __restrict__ cur8) {
  int i = blockIdx.x * 256 + threadIdx.x;
  if (i < NN) {
    int o = offs[i];
#pragma unroll
    for (int q = 0; q < 8; ++q) {
      cur8[q * NN + i] = o;
      o += cd8[q * NN + i];
    }
  }
}

// fill CSR + out-degree partials (same grid/partition mapping as k_hist)
__global__ void k_fill(const int* __restrict__ src, const int* __restrict__ dst,
                       int* __restrict__ cur8, int* __restrict__ csr,
                       int* __restrict__ cs8) {
  int e = blockIdx.x * 256 + threadIdx.x;
  int q = blockIdx.x & 7;
  if (e < NE) {
    int s = src[e];
    atomicAdd(&cs8[q * NN + s], 1);
    int p = atomicAdd(&cur8[q * NN + dst[e]], 1);
    csr[p] = s;
  }
}

// reduce cs8 -> ns
__global__ void k_csred(const int* __restrict__ cs8, float* __restrict__ ns) {
  int i = blockIdx.x * 256 + threadIdx.x;
  if (i < NN) {
    int c = 0;
#pragma unroll
    for (int q = 0; q < 8; ++q) c += cs8[q * NN + i];
    ns[i] = rsqrtf(fmaxf((float)c, 1.f));
  }
}

// ---------------- pull: pipelined gather, wave per node ----------------
__device__ __forceinline__ float rl_f(float v, int idx) {
  return __int_as_float(__builtin_amdgcn_readlane(__float_as_int(v), idx));
}

__global__ __launch_bounds__(256) void k_pull(const f16* __restrict__ hh,
    const float* __restrict__ ns, const float* __restrict__ nd,
    const int* __restrict__ offs, const int* __restrict__ csr,
    f16* __restrict__ aggt) {
  int wid = (blockIdx.x * 256 + threadIdx.x) >> 6;
  int lane = threadIdx.x & 63;
  if (wid >= NN) return;
  int lo = offs[wid], hi = offs[wid + 1];
  f32x4 acc = (f32x4)0.f;
  const f16* hcol = hh + 4 * lane;

  for (int b0 = lo; b0 < hi; b0 += 64) {
    int cnt = min(64, hi - b0);
    int sv = 0; float nv = 0.f;
    if (lane < cnt) { sv = csr[b0 + lane]; nv = ns[sv]; }
    if (lane < 37) {
      int g = 0;
      for (; g + 8 <= cnt; g += 8) {
        int s[8]; float w[8]; f16x4 r[8];
#pragma unroll
        for (int j = 0; j < 8; ++j) {
          s[j] = __builtin_amdgcn_readlane(sv, g + j);
          w[j] = rl_f(nv, g + j);
        }
#pragma unroll
        for (int j = 0; j < 8; ++j) r[j] = *(const f16x4*)(hcol + (size_t)s[j] * SP);
#pragma unroll
        for (int j = 0; j < 8; ++j) {
          acc[0] = fmaf(w[j], (float)r[j][0], acc[0]);
          acc[1] = fmaf(w[j], (float)r[j][1], acc[1]);
          acc[2] = fmaf(w[j], (float)r[j][2], acc[2]);
          acc[3] = fmaf(w[j], (float)r[j][3], acc[3]);
        }
      }
      for (; g < cnt; g += 4) {
        int s[4]; float w[4]; f16x4 r[4];
#pragma unroll
        for (int j = 0; j < 4; ++j) {
          int e = g + j;
          int ec = (e < cnt) ? e : (cnt - 1);
          s[j] = __builtin_amdgcn_readlane(sv, ec);
          float ww = rl_f(nv, ec);
          w[j] = (e < cnt) ? ww : 0.f;
        }
#pragma unroll
        for (int j = 0; j < 4; ++j) r[j] = *(const f16x4*)(hcol + (size_t)s[j] * SP);
#pragma unroll
        for (int j = 0; j < 4; ++j) {
          acc[0] = fmaf(w[j], (float)r[j][0], acc[0]);
          acc[1] = fmaf(w[j], (float)r[j][1], acc[1]);
          acc[2] = fmaf(w[j], (float)r[j][2], acc[2]);
          acc[3] = fmaf(w[j], (float)r[j][3], acc[3]);
        }
      }
    }
  }

  if (lane < 40) {
    float sc = nd[wid];
    int B = wid >> 4, pos = wid & 15;
    int c = 4 * lane;
    f16x4 o = (f16x4)(f16)0;
    if (lane < 37) {
      o[0] = (f16)(acc[0] * sc);
      o[1] = (f16)(acc[1] * sc);
      o[2] = (f16)(acc[2] * sc);
      o[3] = (f16)(acc[3] * sc);
    }
    *(f16x4*)(aggt + ((size_t)(B * 20 + (c >> 3)) * 16 + pos) * 8 + (c & 7)) = o;
  }
}

// ---------------- one-shot prep ----------------
__global__ void k_prep(const float* __restrict__ W_e, const float* __restrict__ W1,
                       const float* __restrict__ W2, const float* __restrict__ W3,
                       const float* __restrict__ b_e, const float* __restrict__ b1,
                       const float* __restrict__ b2, const float* __restrict__ b3,
                       f16* __restrict__ WtE, f16* __restrict__ Wt,
                       float* __restrict__ bp) {
  int idx = blockIdx.x * 256 + threadIdx.x;
  if (idx < 10240) {
    int j = idx & 7, pos = (idx >> 3) & 15;
    int rem = idx >> 7;
    int kg = rem & 7, cb = rem >> 3;
    int c = cb * 16 + pos, k = kg * 8 + j;
    WtE[idx] = (c < HD) ? (f16)W_e[k * HD + c] : (f16)0;
  } else if (idx < 87040) {
    int i2 = idx - 10240;
    int l = i2 / 25600, m = i2 % 25600;
    const float* W = (l == 0) ? W1 : (l == 1) ? W2 : W3;
    int j = m & 7, pos = (m >> 3) & 15;
    int rem = m >> 7;
    int kg = rem % 20, cb = rem / 20;
    int c = cb * 16 + pos, k = kg * 8 + j;
    Wt[i2] = (k < HD && c < HD) ? (f16)W[k * HD + c] : (f16)0;
  } else if (idx < 87680) {
    int i2 = idx - 87040;
    int which = i2 / 160, t = i2 % 160;
    const float* b = (which == 0) ? b_e : (which == 1) ? b1 : (which == 2) ? b2 : b3;
    bp[i2] = (t < HD) ? b[t] : 0.f;
  }
}

// graph row bounds
__global__ void k_gbounds(const int* __restrict__ gid, int* __restrict__ gb) {
  int g = threadIdx.x;
  if (g > NG) return;
  int lo = 0, hi = NN;
  while (lo < hi) {
    int m = (lo + hi) >> 1;
    if (gid[m] < g) lo = m + 1; else hi = m;
  }
  gb[g] = lo;
}

// X fp32 [NN][64] -> Xt tiled [NRB][8 kg][16 pos][8 j]
__global__ void k_convX(const float* __restrict__ X, f16* __restrict__ Xt) {
  int i = blockIdx.x * 256 + threadIdx.x;
  if (i >= NRB * 8 * 16) return;
  int pos = i & 15, kg = (i >> 4) & 7, RB = i >> 7;
  const float* src = X + ((size_t)RB * 16 + pos) * 64 + kg * 8;
  f16x8 v;
#pragma unroll
  for (int j = 0; j < 8; ++j) v[j] = (f16)src[j];
  *(f16x8*)(Xt + (size_t)i * 8) = v;
}

// ---------------- MFMA GEMM ----------------
// LAYER: out h2 f16 [NN][160] (+bias,*snorm); BN partial sums -> stp[block][320]
// !LAYER: out hh f16 [NN][SP] (+bias, zeros in pad cols)
template<int KG, int NSTEP, bool LAYER>
__global__ __launch_bounds__(256) void k_mfma(
    const f16* __restrict__ At, const f16* __restrict__ Wt,
    const float* __restrict__ bp, const float* __restrict__ snorm,
    f16* __restrict__ Hh, f16* __restrict__ Ch, float* __restrict__ stp) {
  __shared__ __align__(16) f16 As[8 * 512];
  __shared__ __align__(16) f16 Ws[10 * 512];
  __shared__ float bsum[160], bsq[160];

  int t = threadIdx.x;
  int w = t >> 6, l = t & 63;
  int wr = w >> 1, wc = w & 1;
  int l15 = l & 15, l4 = l >> 4;
  int RB0 = blockIdx.x * 8;

  if (LAYER && t < 160) { bsum[t] = 0.f; bsq[t] = 0.f; }

  f32x4 acc[4][5];
#pragma unroll
  for (int i = 0; i < 4; ++i)
#pragma unroll
    for (int j = 0; j < 5; ++j) acc[i][j] = (f32x4)0.f;

#pragma unroll 1
  for (int s = 0; s < NSTEP; ++s) {
    __syncthreads();
#pragma unroll
    for (int u = 0; u < 2; ++u) {
      int i = t + u * 256;
      int rb = i >> 6, p = i & 63;
      int RB = RB0 + rb;
      f16x8 v = (f16x8)(f16)0;
      if (RB < NRB) v = *(const f16x8*)(At + ((size_t)RB * KG + 4 * s) * 128 + p * 8);
      *(f16x8*)(As + rb * 512 + p * 8) = v;
    }
#pragma unroll
    for (int u = 0; u < 3; ++u) {
      int m = t + u * 256;
      if (m < 640) {
        int cb = m >> 6, p = m & 63;
        f16x8 v = *(const f16x8*)(Wt + ((size_t)cb * KG + 4 * s) * 128 + p * 8);
        *(f16x8*)(Ws + cb * 512 + p * 8) = v;
      }
    }
    __syncthreads();

    f16x8 af[4], bf[5];
#pragma unroll
    for (int i = 0; i < 4; ++i)
      af[i] = *(const f16x8*)(As + (wr * 4 + i) * 512 + l4 * 128 + l15 * 8);
#pragma unroll
    for (int j = 0; j < 5; ++j)
      bf[j] = *(const f16x8*)(Ws + (wc * 5 + j) * 512 + l4 * 128 + l15 * 8);
#pragma unroll
    for (int i = 0; i < 4; ++i)
#pragma unroll
      for (int j = 0; j < 5; ++j)
        acc[i][j] = __builtin_amdgcn_mfma_f32_16x16x32_f16(af[i], bf[j], acc[i][j], 0, 0, 0);
  }

  float cs[5], cq[5];
#pragma unroll
  for (int j = 0; j < 5; ++j) { cs[j] = 0.f; cq[j] = 0.f; }

  int colbase = wc * 80;
  int rowbase = RB0 * 16 + wr * 64;
#pragma unroll
  for (int i = 0; i < 4; ++i) {
#pragma unroll
    for (int r = 0; r < 4; ++r) {
      int row = rowbase + i * 16 + l4 * 4 + r;
      bool ok = row < NN;
      float sn = 1.f;
      if (LAYER && ok) sn = snorm[row];
#pragma unroll
      for (int j = 0; j < 5; ++j) {
        int col = colbase + j * 16 + l15;
        float v = acc[i][j][r] + bp[col];
        if (LAYER) {
          v *= sn;
          if (ok) {
            Ch[(size_t)row * 160 + col] = (f16)v;
            cs[j] += v;
            cq[j] = fmaf(v, v, cq[j]);
          }
        } else {
          if (ok) {
            if (col < HD) Hh[(size_t)row * SP + col] = (f16)v;
            else if (col < SP) Hh[(size_t)row * SP + col] = (f16)0;
          }
        }
      }
    }
  }
  if (LAYER) {
#pragma unroll
    for (int j = 0; j < 5; ++j) {
      int col = colbase + j * 16 + l15;
      atomicAdd(&bsum[col], cs[j]);
      atomicAdd(&bsq[col], cq[j]);
    }
    __syncthreads();
    if (t < 160) {
      stp[(size_t)blockIdx.x * 320 + t] = bsum[t];
      stp[(size_t)blockIdx.x * 320 + 160 + t] = bsq[t];
    }
  }
}

// reduce stp[GB][320] -> stsum[320]
__global__ void k_stred(const float* __restrict__ stp, float* __restrict__ stsum) {
  int c = blockIdx.x;   // 0..319
  int t = threadIdx.x;  // 128
  float s = 0.f;
  for (int i = t; i < GB; i += 128) s += stp[(size_t)i * 320 + c];
  __shared__ float sm[128];
  sm[t] = s; __syncthreads();
  for (int o = 64; o > 0; o >>= 1) {
    if (t < o) sm[t] += sm[t + o];
    __syncthreads();
  }
  if (t == 0) stsum[c] = sm[0];
}

// ---------------- update (BN finalize fused): hh += relu(h2*a+b2) ----------------
__global__ __launch_bounds__(256) void k_update(const f16* __restrict__ h2,
    const float* __restrict__ st, const float* __restrict__ g,
    const float* __restrict__ bt, f16* __restrict__ hh) {
  __shared__ float ab[320];
  int t = threadIdx.x;
  if (t < 160) {
    float m = st[t] * (1.f / NN);
    float q = st[160 + t] * (1.f / NN);
    float iv = rsqrtf(q - m * m + EPSF);
    float gg = (t < HD) ? g[t] : 0.f;
    float bb = (t < HD) ? bt[t] : 0.f;
    float a = iv * gg;
    ab[t] = a;
    ab[160 + t] = bb - m * a;
  }
  __syncthreads();
  const int total = NN * 37;
  int stride = gridDim.x * 256;
  for (int idx = blockIdx.x * 256 + t; idx < total; idx += stride) {
    int r = idx / 37, gq = idx - r * 37;
    int c = gq * 4;
    f16x4 p = *(const f16x4*)(h2 + (size_t)r * 160 + c);
    f16x4 hv = *(const f16x4*)(hh + (size_t)r * SP + c);
    f16x4 ho;
#pragma unroll
    for (int j = 0; j < 4; ++j) {
      float v = fmaf((float)p[j], ab[c + j], ab[160 + c + j]);
      float hn = (float)hv[j] + fmaxf(v, 0.f);
      ho[j] = (f16)hn;
    }
    *(f16x4*)(hh + (size_t)r * SP + c) = ho;
  }
}

// ---------------- readout: per-chunk partials (no global atomics) ----------------
__global__ __launch_bounds__(256) void k_readout1(const f16* __restrict__ hh,
    const int* __restrict__ gb, float* __restrict__ out16) {
  int g = blockIdx.x >> 4, chunk = blockIdx.x & 15;
  int lo = gb[g], hi = gb[g + 1];
  int w = threadIdx.x >> 6, lane = threadIdx.x & 63;
  __shared__ float sacc[148];
  if (threadIdx.x < 148) sacc[threadIdx.x] = 0.f;
  __syncthreads();
  f32x4 acc = (f32x4)0.f;
  if (lane < 37) {
    for (int r = lo + chunk * 4 + w; r < hi; r += 64) {
      f16x4 v = *(const f16x4*)(hh + (size_t)r * SP + lane * 4);
      acc[0] += (float)v[0];
      acc[1] += (float)v[1];
      acc[2] += (float)v[2];
      acc[3] += (float)v[3];
    }
    atomicAdd(&sacc[lane * 4 + 0], acc[0]);
    atomicAdd(&sacc[lane * 4 + 1], acc[1]);
    atomicAdd(&sacc[lane * 4 + 2], acc[2]);
    atomicAdd(&sacc[lane * 4 + 3], acc[3]);
  }
  __syncthreads();
  if (threadIdx.x < 148)
    out16[((size_t)chunk * NG + g) * 148 + threadIdx.x] = sacc[threadIdx.x];
}

__global__ void k_rdiv(const int* __restrict__ gb, const float* __restrict__ out16,
                       float* __restrict__ out) {
  int g = blockIdx.x, c = threadIdx.x;
  if (c < HD) {
    float s = 0.f;
#pragma unroll
    for (int ch = 0; ch < 16; ++ch) s += out16[((size_t)ch * NG + g) * 148 + c];
    out[g * HD + c] = s / fmaxf((float)(gb[g + 1] - gb[g]), 1.f);
  }
}

extern "C" void kernel_launch(void* const* d_in, const int* in_sizes, int n_in,
                              void* d_out, int out_size, void* d_ws, size_t ws_size,
                              hipStream_t stream) {
  const float* X     = (const float*)d_in[0];
  const float* snorm = (const float*)d_in[1];
  const float* W_e   = (const float*)d_in[2];
  const float* b_e   = (const float*)d_in[3];
  const float* Wl[3]  = {(const float*)d_in[4], (const float*)d_in[8],  (const float*)d_in[12]};
  const float* bl[3]  = {(const float*)d_in[5], (const float*)d_in[9],  (const float*)d_in[13]};
  const float* gl[3]  = {(const float*)d_in[6], (const float*)d_in[10], (const float*)d_in[14]};
  const float* btl[3] = {(const float*)d_in[7], (const float*)d_in[11], (const float*)d_in[15]};
  const int* src = (const int*)d_in[16];
  const int* dst = (const int*)d_in[17];
  const int* gid = (const int*)d_in[18];
  float* out = (float*)d_out;

  char* p = (char*)d_ws;
  f16* hh    = (f16*)p;   p += sizeof(f16) * (size_t)NN * SP;          // 29.6 MB
  f16* aggt  = (f16*)p;   p += sizeof(f16) * (size_t)NRB * 20 * 128;   // 32 MB (Xt & h2 alias)
  f16* WtE   = (f16*)p;   p += sizeof(f16) * 10240;
  f16* Wt    = (f16*)p;   p += sizeof(f16) * 3 * 25600;
  float* bp  = (float*)p; p += sizeof(float) * 4 * 160;
  float* stp = (float*)p; p += sizeof(float) * (size_t)GB * 320;       // 1 MB
  float* stsum = (float*)p; p += sizeof(float) * 320;
  float* out16 = (float*)p; p += sizeof(float) * 16 * NG * 148;        // 2.4 MB
  float* ns  = (float*)p; p += sizeof(float) * NN;
  float* nd  = (float*)p; p += sizeof(float) * NN;
  int* cd8  = (int*)p; p += sizeof(int) * 8 * NN;                      // 3.2 MB
  int* cs8  = (int*)p; p += sizeof(int) * 8 * NN;                      // 3.2 MB
  int* cur8 = (int*)p; p += sizeof(int) * 8 * NN;                      // 3.2 MB
  int* cd   = (int*)p; p += sizeof(int) * NN;
  int* offs = (int*)p; p += sizeof(int) * (NN + 1);
  int* part = (int*)p; p += sizeof(int) * 512;
  int* gb   = (int*)p; p += sizeof(int) * (NG + 1);
  int* csr  = (int*)p; p += sizeof(int) * NE;

  f16* Xt = aggt;
  f16* h2 = aggt;

  hipMemsetAsync(cd8, 0, sizeof(int) * 16 * (size_t)NN, stream);   // cd8 & cs8 contiguous

  const int EB = (NE + 255) / 256;
  k_hist <<<EB, 256, 0, stream>>>(dst, cd8);
  k_cdred<<<NSB, 256, 0, stream>>>(cd8, cd, nd);
  k_scan1<<<NSB, 256, 0, stream>>>(cd, offs, part);
  k_scan2<<<1, 512, 0, stream>>>(part);
  k_scan3<<<NSB, 256, 0, stream>>>(offs, part);
  k_bases<<<NSB, 256, 0, stream>>>(offs, cd8, cur8);
  k_fill <<<EB, 256, 0, stream>>>(src, dst, cur8, csr, cs8);
  k_csred<<<NSB, 256, 0, stream>>>(cs8, ns);

  k_prep<<<343, 256, 0, stream>>>(W_e, Wl[0], Wl[1], Wl[2], b_e, bl[0], bl[1], bl[2],
                                  WtE, Wt, bp);
  k_gbounds<<<1, 512, 0, stream>>>(gid, gb);

  k_convX<<<(NRB * 8 * 16 + 255) / 256, 256, 0, stream>>>(X, Xt);
  k_mfma<8, 2, false><<<GB, 256, 0, stream>>>(Xt, WtE, bp, nullptr, hh, nullptr, nullptr);

  for (int l = 0; l < 3; ++l) {
    k_pull<<<(NN * 64 + 255) / 256, 256, 0, stream>>>(hh, ns, nd, offs, csr, aggt);
    k_mfma<20, 5, true><<<GB, 256, 0, stream>>>(aggt, Wt + l * 25600, bp + (l + 1) * 160,
                                                snorm, nullptr, h2, stp);
    k_stred<<<320, 128, 0, stream>>>(stp, stsum);
    k_update<<<4096, 256, 0, stream>>>(h2, stsum, gl[l], btl[l], hh);
  }

  k_readout1<<<NG * 16, 256, 0, stream>>>(hh, gb, out16);
  k_rdiv<<<NG, 192, 0, stream>>>(gb, out16, out);
}

// Round 11
// 567.768 us; speedup vs baseline: 7.1345x; 1.0892x over previous
//
#include <hip/hip_runtime.h>

#define NN 100000
#define NE 1000000
#define NG 256
#define HD 146
#define SP 152          // padded row stride for hh (f16): 19 x f16x8
#define EPSF 1e-5f
#define NSB 391         // ceil(NN/256)
#define NRB 6250        // NN/16 row-blocks (exact)
#define GB 782          // MFMA grid = ceil(NRB/8)
#define BCAP 64         // bucket capacity (P(deg>=64) ~ 1e-31 for Poisson(10))

typedef _Float16 f16;
typedef f16 f16x8 __attribute__((ext_vector_type(8)));
typedef f16 f16x4 __attribute__((ext_vector_type(4)));
typedef float f32x4 __attribute__((ext_vector_type(4)));

// ---------------- one-pass CSR build: bucket[dst] + out-degree histogram ----------------
__global__ void k_build(const int* __restrict__ src, const int* __restrict__ dst,
                        int* __restrict__ cnt, int* __restrict__ buck,
                        int* __restrict__ cs) {
  int e = blockIdx.x * 256 + threadIdx.x;
  if (e < NE) {
    int s = src[e];
    atomicAdd(&cs[s], 1);
    int d = dst[e];
    int p = atomicAdd(&cnt[d], 1);
    if (p < BCAP) buck[(size_t)d * BCAP + p] = s;
  }
}

__global__ void k_norms(const int* __restrict__ cs, const int* __restrict__ cnt,
                        float* __restrict__ ns, float* __restrict__ nd) {
  int i = blockIdx.x * 256 + threadIdx.x;
  if (i < NN) {
    ns[i] = rsqrtf(fmaxf((float)cs[i], 1.f));
    nd[i] = rsqrtf(fmaxf((float)cnt[i], 1.f));
  }
}

// ---------------- pull: 3 edges/wave-iter, f16x8 lanes, bpermute edge fetch ----------------
__global__ __launch_bounds__(256) void k_pull(const f16* __restrict__ hh,
    const float* __restrict__ ns, const float* __restrict__ nd,
    const int* __restrict__ cnt, const int* __restrict__ buck,
    f16* __restrict__ aggt) {
  int wid = (blockIdx.x * 256 + threadIdx.x) >> 6;
  int lane = threadIdx.x & 63;
  if (wid >= NN) return;
  int deg = min(cnt[wid], BCAP);

  int sv = 0; float nv = 0.f;
  if (lane < deg) { sv = buck[(size_t)wid * BCAP + lane]; nv = ns[sv]; }

  int sub = lane / 19;            // 0..2 active edge-groups (lanes 57..63: sub=3, idle)
  int grp = lane - sub * 19;      // 0..18 -> cols [grp*8, grp*8+8)
  bool act = lane < 57;
  const f16* hcol = hh + grp * 8;

  float acc[8];
#pragma unroll
  for (int k = 0; k < 8; ++k) acc[k] = 0.f;

  for (int g = 0; g < deg; g += 12) {
    int s[4]; float w[4]; f16x8 r[4];
#pragma unroll
    for (int u = 0; u < 4; ++u) {
      int e = g + sub + 3 * u;
      int ec = (e < deg) ? e : 0;
      // per-lane pull (ds_bpermute) -- divergent index is well-defined, unlike readlane
      s[u] = __shfl(sv, ec, 64);
      float ww = __shfl(nv, ec, 64);
      w[u] = (e < deg && act) ? ww : 0.f;
    }
#pragma unroll
    for (int u = 0; u < 4; ++u) r[u] = *(const f16x8*)(hcol + (size_t)s[u] * SP);
#pragma unroll
    for (int u = 0; u < 4; ++u)
#pragma unroll
      for (int k = 0; k < 8; ++k)
        acc[k] = fmaf(w[u], (float)r[u][k], acc[k]);
  }

  // reduce across the 3 sub-groups: lane<19 collects lane+19, lane+38
#pragma unroll
  for (int k = 0; k < 8; ++k) {
    float a1 = __shfl(acc[k], lane + 19, 64);
    float a2 = __shfl(acc[k], lane + 38, 64);
    acc[k] += a1 + a2;
  }

  if (lane < 20) {   // lane<19: cols [lane*8, +8); lane 19: zero kg=19 (cols 152..159)
    float sc = nd[wid];
    int B = wid >> 4, pos = wid & 15;
    f16x8 o = (f16x8)(f16)0;
    if (lane < 19) {
#pragma unroll
      for (int k = 0; k < 8; ++k) o[k] = (f16)(acc[k] * sc);
    }
    *(f16x8*)(aggt + ((size_t)(B * 20 + lane) * 16 + pos) * 8) = o;
  }
}

// ---------------- one-shot prep ----------------
__global__ void k_prep(const float* __restrict__ W_e, const float* __restrict__ W1,
                       const float* __restrict__ W2, const float* __restrict__ W3,
                       const float* __restrict__ b_e, const float* __restrict__ b1,
                       const float* __restrict__ b2, const float* __restrict__ b3,
                       f16* __restrict__ WtE, f16* __restrict__ Wt,
                       float* __restrict__ bp) {
  int idx = blockIdx.x * 256 + threadIdx.x;
  if (idx < 10240) {                       // W_e [64][146] -> [10 cb][8 kg][16][8]
    int j = idx & 7, pos = (idx >> 3) & 15;
    int rem = idx >> 7;
    int kg = rem & 7, cb = rem >> 3;
    int c = cb * 16 + pos, k = kg * 8 + j;
    WtE[idx] = (c < HD) ? (f16)W_e[k * HD + c] : (f16)0;
  } else if (idx < 87040) {                // W_l [146][146] -> [10 cb][20 kg][16][8] x3
    int i2 = idx - 10240;
    int l = i2 / 25600, m = i2 % 25600;
    const float* W = (l == 0) ? W1 : (l == 1) ? W2 : W3;
    int j = m & 7, pos = (m >> 3) & 15;
    int rem = m >> 7;
    int kg = rem % 20, cb = rem / 20;
    int c = cb * 16 + pos, k = kg * 8 + j;
    Wt[i2] = (k < HD && c < HD) ? (f16)W[k * HD + c] : (f16)0;
  } else if (idx < 87680) {                // biases padded to 160, x4
    int i2 = idx - 87040;
    int which = i2 / 160, t = i2 % 160;
    const float* b = (which == 0) ? b_e : (which == 1) ? b1 : (which == 2) ? b2 : b3;
    bp[i2] = (t < HD) ? b[t] : 0.f;
  }
}

// graph row bounds
__global__ void k_gbounds(const int* __restrict__ gid, int* __restrict__ gb) {
  int g = threadIdx.x;
  if (g > NG) return;
  int lo = 0, hi = NN;
  while (lo < hi) {
    int m = (lo + hi) >> 1;
    if (gid[m] < g) lo = m + 1; else hi = m;
  }
  gb[g] = lo;
}

// X fp32 [NN][64] -> Xt tiled [NRB][8 kg][16 pos][8 j]
__global__ void k_convX(const float* __restrict__ X, f16* __restrict__ Xt) {
  int i = blockIdx.x * 256 + threadIdx.x;
  if (i >= NRB * 8 * 16) return;
  int pos = i & 15, kg = (i >> 4) & 7, RB = i >> 7;
  const float* src = X + ((size_t)RB * 16 + pos) * 64 + kg * 8;
  f16x8 v;
#pragma unroll
  for (int j = 0; j < 8; ++j) v[j] = (f16)src[j];
  *(f16x8*)(Xt + (size_t)i * 8) = v;
}

// ---------------- MFMA GEMM ----------------
// LAYER: out h2 f16 [NN][160] (+bias,*snorm); BN partial sums -> stp[block][320]
// !LAYER: out hh f16 [NN][SP] (+bias, zeros in pad cols 146..151)
template<int KG, int NSTEP, bool LAYER>
__global__ __launch_bounds__(256) void k_mfma(
    const f16* __restrict__ At, const f16* __restrict__ Wt,
    const float* __restrict__ bp, const float* __restrict__ snorm,
    f16* __restrict__ Hh, f16* __restrict__ Ch, float* __restrict__ stp) {
  __shared__ __align__(16) f16 As[8 * 512];
  __shared__ __align__(16) f16 Ws[10 * 512];
  __shared__ float bsum[160], bsq[160];

  int t = threadIdx.x;
  int w = t >> 6, l = t & 63;
  int wr = w >> 1, wc = w & 1;
  int l15 = l & 15, l4 = l >> 4;
  int RB0 = blockIdx.x * 8;

  if (LAYER && t < 160) { bsum[t] = 0.f; bsq[t] = 0.f; }

  f32x4 acc[4][5];
#pragma unroll
  for (int i = 0; i < 4; ++i)
#pragma unroll
    for (int j = 0; j < 5; ++j) acc[i][j] = (f32x4)0.f;

#pragma unroll 1
  for (int s = 0; s < NSTEP; ++s) {
    __syncthreads();
#pragma unroll
    for (int u = 0; u < 2; ++u) {
      int i = t + u * 256;
      int rb = i >> 6, p = i & 63;
      int RB = RB0 + rb;
      f16x8 v = (f16x8)(f16)0;
      if (RB < NRB) v = *(const f16x8*)(At + ((size_t)RB * KG + 4 * s) * 128 + p * 8);
      *(f16x8*)(As + rb * 512 + p * 8) = v;
    }
#pragma unroll
    for (int u = 0; u < 3; ++u) {
      int m = t + u * 256;
      if (m < 640) {
        int cb = m >> 6, p = m & 63;
        f16x8 v = *(const f16x8*)(Wt + ((size_t)cb * KG + 4 * s) * 128 + p * 8);
        *(f16x8*)(Ws + cb * 512 + p * 8) = v;
      }
    }
    __syncthreads();

    f16x8 af[4], bf[5];
#pragma unroll
    for (int i = 0; i < 4; ++i)
      af[i] = *(const f16x8*)(As + (wr * 4 + i) * 512 + l4 * 128 + l15 * 8);
#pragma unroll
    for (int j = 0; j < 5; ++j)
      bf[j] = *(const f16x8*)(Ws + (wc * 5 + j) * 512 + l4 * 128 + l15 * 8);
#pragma unroll
    for (int i = 0; i < 4; ++i)
#pragma unroll
      for (int j = 0; j < 5; ++j)
        acc[i][j] = __builtin_amdgcn_mfma_f32_16x16x32_f16(af[i], bf[j], acc[i][j], 0, 0, 0);
  }

  float cs[5], cq[5];
#pragma unroll
  for (int j = 0; j < 5; ++j) { cs[j] = 0.f; cq[j] = 0.f; }

  int colbase = wc * 80;
  int rowbase = RB0 * 16 + wr * 64;
#pragma unroll
  for (int i = 0; i < 4; ++i) {
#pragma unroll
    for (int r = 0; r < 4; ++r) {
      int row = rowbase + i * 16 + l4 * 4 + r;
      bool ok = row < NN;
      float sn = 1.f;
      if (LAYER && ok) sn = snorm[row];
#pragma unroll
      for (int j = 0; j < 5; ++j) {
        int col = colbase + j * 16 + l15;
        float v = acc[i][j][r] + bp[col];
        if (LAYER) {
          v *= sn;
          if (ok) {
            Ch[(size_t)row * 160 + col] = (f16)v;
            cs[j] += v;
            cq[j] = fmaf(v, v, cq[j]);
          }
        } else {
          if (ok) {
            if (col < HD) Hh[(size_t)row * SP + col] = (f16)v;
            else if (col < SP) Hh[(size_t)row * SP + col] = (f16)0;
          }
        }
      }
    }
  }
  if (LAYER) {
#pragma unroll
    for (int j = 0; j < 5; ++j) {
      int col = colbase + j * 16 + l15;
      atomicAdd(&bsum[col], cs[j]);
      atomicAdd(&bsq[col], cq[j]);
    }
    __syncthreads();
    if (t < 160) {
      stp[(size_t)blockIdx.x * 320 + t] = bsum[t];
      stp[(size_t)blockIdx.x * 320 + 160 + t] = bsq[t];
    }
  }
}

// reduce stp[GB][320] -> stsum[320]
__global__ void k_stred(const float* __restrict__ stp, float* __restrict__ stsum) {
  int c = blockIdx.x;   // 0..319
  int t = threadIdx.x;  // 128
  float s = 0.f;
  for (int i = t; i < GB; i += 128) s += stp[(size_t)i * 320 + c];
  __shared__ float sm[128];
  sm[t] = s; __syncthreads();
  for (int o = 64; o > 0; o >>= 1) {
    if (t < o) sm[t] += sm[t + o];
    __syncthreads();
  }
  if (t == 0) stsum[c] = sm[0];
}

// ---------------- update (BN finalize fused): hh += relu(h2*a+b2) ----------------
__global__ __launch_bounds__(256) void k_update(const f16* __restrict__ h2,
    const float* __restrict__ st, const float* __restrict__ g,
    const float* __restrict__ bt, f16* __restrict__ hh) {
  __shared__ float ab[320];
  int t = threadIdx.x;
  if (t < 160) {
    float m = st[t] * (1.f / NN);
    float q = st[160 + t] * (1.f / NN);
    float iv = rsqrtf(q - m * m + EPSF);
    float gg = (t < HD) ? g[t] : 0.f;
    float bb = (t < HD) ? bt[t] : 0.f;
    float a = iv * gg;
    ab[t] = a;
    ab[160 + t] = bb - m * a;
  }
  __syncthreads();
  const int total = NN * 38;     // cols 0..151 (pads get +relu(0)=0, stay zero)
  int stride = gridDim.x * 256;
  for (int idx = blockIdx.x * 256 + t; idx < total; idx += stride) {
    int r = idx / 38, gq = idx - r * 38;
    int c = gq * 4;
    f16x4 p = *(const f16x4*)(h2 + (size_t)r * 160 + c);
    f16x4 hv = *(const f16x4*)(hh + (size_t)r * SP + c);
    f16x4 ho;
#pragma unroll
    for (int j = 0; j < 4; ++j) {
      float v = fmaf((float)p[j], ab[c + j], ab[160 + c + j]);
      float hn = (float)hv[j] + fmaxf(v, 0.f);
      ho[j] = (f16)hn;
    }
    *(f16x4*)(hh + (size_t)r * SP + c) = ho;
  }
}

// ---------------- readout: per-chunk partials (no global atomics) ----------------
__global__ __launch_bounds__(256) void k_readout1(const f16* __restrict__ hh,
    const int* __restrict__ gb, float* __restrict__ out16) {
  int g = blockIdx.x >> 4, chunk = blockIdx.x & 15;
  int lo = gb[g], hi = gb[g + 1];
  int w = threadIdx.x >> 6, lane = threadIdx.x & 63;
  __shared__ float sacc[148];
  if (threadIdx.x < 148) sacc[threadIdx.x] = 0.f;
  __syncthreads();
  f32x4 acc = (f32x4)0.f;
  if (lane < 37) {
    for (int r = lo + chunk * 4 + w; r < hi; r += 64) {
      f16x4 v = *(const f16x4*)(hh + (size_t)r * SP + lane * 4);
      acc[0] += (float)v[0];
      acc[1] += (float)v[1];
      acc[2] += (float)v[2];
      acc[3] += (float)v[3];
    }
    atomicAdd(&sacc[lane * 4 + 0], acc[0]);
    atomicAdd(&sacc[lane * 4 + 1], acc[1]);
    atomicAdd(&sacc[lane * 4 + 2], acc[2]);
    atomicAdd(&sacc[lane * 4 + 3], acc[3]);
  }
  __syncthreads();
  if (threadIdx.x < 148)
    out16[((size_t)chunk * NG + g) * 148 + threadIdx.x] = sacc[threadIdx.x];
}

__global__ void k_rdiv(const int* __restrict__ gb, const float* __restrict__ out16,
                       float* __restrict__ out) {
  int g = blockIdx.x, c = threadIdx.x;
  if (c < HD) {
    float s = 0.f;
#pragma unroll
    for (int ch = 0; ch < 16; ++ch) s += out16[((size_t)ch * NG + g) * 148 + c];
    out[g * HD + c] = s / fmaxf((float)(gb[g + 1] - gb[g]), 1.f);
  }
}

extern "C" void kernel_launch(void* const* d_in, const int* in_sizes, int n_in,
                              void* d_out, int out_size, void* d_ws, size_t ws_size,
                              hipStream_t stream) {
  const float* X     = (const float*)d_in[0];
  const float* snorm = (const float*)d_in[1];
  const float* W_e   = (const float*)d_in[2];
  const float* b_e   = (const float*)d_in[3];
  const float* Wl[3]  = {(const float*)d_in[4], (const float*)d_in[8],  (const float*)d_in[12]};
  const float* bl[3]  = {(const float*)d_in[5], (const float*)d_in[9],  (const float*)d_in[13]};
  const float* gl[3]  = {(const float*)d_in[6], (const float*)d_in[10], (const float*)d_in[14]};
  const float* btl[3] = {(const float*)d_in[7], (const float*)d_in[11], (const float*)d_in[15]};
  const int* src = (const int*)d_in[16];
  const int* dst = (const int*)d_in[17];
  const int* gid = (const int*)d_in[18];
  float* out = (float*)d_out;

  char* p = (char*)d_ws;
  f16* hh    = (f16*)p;   p += sizeof(f16) * (size_t)NN * SP;          // 30.4 MB
  f16* aggt  = (f16*)p;   p += sizeof(f16) * (size_t)NRB * 20 * 128;   // 32 MB (Xt & h2 alias)
  f16* WtE   = (f16*)p;   p += sizeof(f16) * 10240;
  f16* Wt    = (f16*)p;   p += sizeof(f16) * 3 * 25600;
  float* bp  = (float*)p; p += sizeof(float) * 4 * 160;
  float* stp = (float*)p; p += sizeof(float) * (size_t)GB * 320;       // 1 MB
  float* stsum = (float*)p; p += sizeof(float) * 320;
  float* out16 = (float*)p; p += sizeof(float) * 16 * NG * 148;        // 2.4 MB
  float* ns  = (float*)p; p += sizeof(float) * NN;
  float* nd  = (float*)p; p += sizeof(float) * NN;
  int* cnt  = (int*)p; p += sizeof(int) * NN;                          // in-degree
  int* cs   = (int*)p; p += sizeof(int) * NN;                          // out-degree
  int* gb   = (int*)p; p += sizeof(int) * (NG + 1);
  int* buck = (int*)p; p += sizeof(int) * (size_t)NN * BCAP;           // 25.6 MB

  f16* Xt = aggt;
  f16* h2 = aggt;

  hipMemsetAsync(cnt, 0, sizeof(int) * 2 * (size_t)NN, stream);   // cnt & cs contiguous

  const int EB = (NE + 255) / 256;
  k_build<<<EB, 256, 0, stream>>>(src, dst, cnt, buck, cs);
  k_norms<<<NSB, 256, 0, stream>>>(cs, cnt, ns, nd);

  k_prep<<<343, 256, 0, stream>>>(W_e, Wl[0], Wl[1], Wl[2], b_e, bl[0], bl[1], bl[2],
                                  WtE, Wt, bp);
  k_gbounds<<<1, 512, 0, stream>>>(gid, gb);

  k_convX<<<(NRB * 8 * 16 + 255) / 256, 256, 0, stream>>>(X, Xt);
  k_mfma<8, 2, false><<<GB, 256, 0, stream>>>(Xt, WtE, bp, nullptr, hh, nullptr, nullptr);

  for (int l = 0; l < 3; ++l) {
    k_pull<<<(NN * 64 + 255) / 256, 256, 0, stream>>>(hh, ns, nd, cnt, buck, aggt);
    k_mfma<20, 5, true><<<GB, 256, 0, stream>>>(aggt, Wt + l * 25600, bp + (l + 1) * 160,
                                                snorm, nullptr, h2, stp);
    k_stred<<<320, 128, 0, stream>>>(stp, stsum);
    k_update<<<4096, 256, 0, stream>>>(h2, stsum, gl[l], btl[l], hh);
  }

  k_readout1<<<NG * 16, 256, 0, stream>>>(hh, gb, out16);
  k_rdiv<<<NG, 192, 0, stream>>>(gb, out16, out);
}

// Round 12
// 567.246 us; speedup vs baseline: 7.1410x; 1.0009x over previous
//
#include <hip/hip_runtime.h>

#define NN 100000
#define NE 1000000
#define NG 256
#define HD 146
#define SP 152          // padded row stride for hh (f16): 19 x f16x8
#define EPSF 1e-5f
#define NSB 391         // ceil(NN/256)
#define NRB 6250        // NN/16 row-blocks (exact)
#define GB 782          // MFMA grid = ceil(NRB/8)
#define BCAP 64         // bucket capacity (P(deg>=64) ~ 1e-31 for Poisson(10))

typedef _Float16 f16;
typedef f16 f16x8 __attribute__((ext_vector_type(8)));
typedef f16 f16x4 __attribute__((ext_vector_type(4)));
typedef float f32x4 __attribute__((ext_vector_type(4)));

// physical XCD id (0..7), wave-uniform [measured: learn_hip m09]
__device__ __forceinline__ int xcc_id() {
  int x;
  asm volatile("s_getreg_b32 %0, hwreg(HW_REG_XCC_ID)" : "=s"(x));
  return x & 7;
}

// ---------------- one-pass CSR build ----------------
// cnt: device-scope (return value = globally unique slot).
// cs8: partitioned by PHYSICAL XCD + workgroup-scope atomic -> executes in local L2,
//      no cross-XCD coherence traffic. Partition q only ever touched by XCD q.
__global__ void k_build(const int* __restrict__ src, const int* __restrict__ dst,
                        int* __restrict__ cnt, int* __restrict__ buck,
                        int* __restrict__ cs8) {
  int e = blockIdx.x * 256 + threadIdx.x;
  int q = xcc_id();
  if (e < NE) {
    int s = src[e];
    __hip_atomic_fetch_add(&cs8[q * NN + s], 1, __ATOMIC_RELAXED,
                           __HIP_MEMORY_SCOPE_WORKGROUP);
    int d = dst[e];
    int p = atomicAdd(&cnt[d], 1);
    if (p < BCAP) buck[(size_t)d * BCAP + p] = s;
  }
}

__global__ void k_norms(const int* __restrict__ cs8, const int* __restrict__ cnt,
                        float* __restrict__ ns, float* __restrict__ nd) {
  int i = blockIdx.x * 256 + threadIdx.x;
  if (i < NN) {
    int c = 0;
#pragma unroll
    for (int q = 0; q < 8; ++q) c += cs8[q * NN + i];
    ns[i] = rsqrtf(fmaxf((float)c, 1.f));
    nd[i] = rsqrtf(fmaxf((float)cnt[i], 1.f));
  }
}

// ---------------- pull: 3 edges/wave-iter, f16x8 lanes, bpermute edge fetch ----------------
__global__ __launch_bounds__(256) void k_pull(const f16* __restrict__ hh,
    const float* __restrict__ ns, const float* __restrict__ nd,
    const int* __restrict__ cnt, const int* __restrict__ buck,
    f16* __restrict__ aggt) {
  int wid = (blockIdx.x * 256 + threadIdx.x) >> 6;
  int lane = threadIdx.x & 63;
  if (wid >= NN) return;
  int deg = min(cnt[wid], BCAP);

  int sv = 0; float nv = 0.f;
  if (lane < deg) { sv = buck[(size_t)wid * BCAP + lane]; nv = ns[sv]; }

  int sub = lane / 19;            // 0..2 active edge-groups (lanes 57..63 idle)
  int grp = lane - sub * 19;      // 0..18 -> cols [grp*8, grp*8+8)
  bool act = lane < 57;
  const f16* hcol = hh + grp * 8;

  float acc[8];
#pragma unroll
  for (int k = 0; k < 8; ++k) acc[k] = 0.f;

  for (int g = 0; g < deg; g += 12) {
    int s[4]; float w[4]; f16x8 r[4];
#pragma unroll
    for (int u = 0; u < 4; ++u) {
      int e = g + sub + 3 * u;
      int ec = (e < deg) ? e : 0;
      s[u] = __shfl(sv, ec, 64);           // ds_bpermute: divergent idx well-defined
      float ww = __shfl(nv, ec, 64);
      w[u] = (e < deg && act) ? ww : 0.f;
    }
#pragma unroll
    for (int u = 0; u < 4; ++u) r[u] = *(const f16x8*)(hcol + (size_t)s[u] * SP);
#pragma unroll
    for (int u = 0; u < 4; ++u)
#pragma unroll
      for (int k = 0; k < 8; ++k)
        acc[k] = fmaf(w[u], (float)r[u][k], acc[k]);
  }

#pragma unroll
  for (int k = 0; k < 8; ++k) {
    float a1 = __shfl(acc[k], lane + 19, 64);
    float a2 = __shfl(acc[k], lane + 38, 64);
    acc[k] += a1 + a2;
  }

  if (lane < 20) {   // lane<19: cols [lane*8,+8); lane 19: zero kg=19 (cols 152..159)
    float sc = nd[wid];
    int B = wid >> 4, pos = wid & 15;
    f16x8 o = (f16x8)(f16)0;
    if (lane < 19) {
#pragma unroll
      for (int k = 0; k < 8; ++k) o[k] = (f16)(acc[k] * sc);
    }
    *(f16x8*)(aggt + ((size_t)(B * 20 + lane) * 16 + pos) * 8) = o;
  }
}

// ---------------- one-shot prep (weights, biases, graph bounds) ----------------
__global__ void k_prep(const float* __restrict__ W_e, const float* __restrict__ W1,
                       const float* __restrict__ W2, const float* __restrict__ W3,
                       const float* __restrict__ b_e, const float* __restrict__ b1,
                       const float* __restrict__ b2, const float* __restrict__ b3,
                       f16* __restrict__ WtE, f16* __restrict__ Wt,
                       float* __restrict__ bp,
                       const int* __restrict__ gid, int* __restrict__ gb) {
  int idx = blockIdx.x * 256 + threadIdx.x;
  if (idx < 10240) {                       // W_e [64][146] -> [10 cb][8 kg][16][8]
    int j = idx & 7, pos = (idx >> 3) & 15;
    int rem = idx >> 7;
    int kg = rem & 7, cb = rem >> 3;
    int c = cb * 16 + pos, k = kg * 8 + j;
    WtE[idx] = (c < HD) ? (f16)W_e[k * HD + c] : (f16)0;
  } else if (idx < 87040) {                // W_l [146][146] -> [10 cb][20 kg][16][8] x3
    int i2 = idx - 10240;
    int l = i2 / 25600, m = i2 % 25600;
    const float* W = (l == 0) ? W1 : (l == 1) ? W2 : W3;
    int j = m & 7, pos = (m >> 3) & 15;
    int rem = m >> 7;
    int kg = rem % 20, cb = rem / 20;
    int c = cb * 16 + pos, k = kg * 8 + j;
    Wt[i2] = (k < HD && c < HD) ? (f16)W[k * HD + c] : (f16)0;
  } else if (idx < 87680) {                // biases padded to 160, x4
    int i2 = idx - 87040;
    int which = i2 / 160, t = i2 % 160;
    const float* b = (which == 0) ? b_e : (which == 1) ? b1 : (which == 2) ? b2 : b3;
    bp[i2] = (t < HD) ? b[t] : 0.f;
  } else if (idx < 88192) {                // graph row bounds (gid sorted)
    int g = idx - 87680;
    if (g <= NG) {
      int lo = 0, hi = NN;
      while (lo < hi) {
        int m = (lo + hi) >> 1;
        if (gid[m] < g) lo = m + 1; else hi = m;
      }
      gb[g] = lo;
    }
  }
}

// X fp32 [NN][64] -> Xt tiled [NRB][8 kg][16 pos][8 j]
__global__ void k_convX(const float* __restrict__ X, f16* __restrict__ Xt) {
  int i = blockIdx.x * 256 + threadIdx.x;
  if (i >= NRB * 8 * 16) return;
  int pos = i & 15, kg = (i >> 4) & 7, RB = i >> 7;
  const float* src = X + ((size_t)RB * 16 + pos) * 64 + kg * 8;
  f16x8 v;
#pragma unroll
  for (int j = 0; j < 8; ++j) v[j] = (f16)src[j];
  *(f16x8*)(Xt + (size_t)i * 8) = v;
}

// ---------------- MFMA GEMM ----------------
// LAYER: out h2 f16 [NN][160] (+bias,*snorm); BN partial sums -> stp[block][320]
// !LAYER: out hh f16 [NN][SP] (+bias, zeros in pad cols 146..151)
template<int KG, int NSTEP, bool LAYER>
__global__ __launch_bounds__(256) void k_mfma(
    const f16* __restrict__ At, const f16* __restrict__ Wt,
    const float* __restrict__ bp, const float* __restrict__ snorm,
    f16* __restrict__ Hh, f16* __restrict__ Ch, float* __restrict__ stp) {
  __shared__ __align__(16) f16 As[8 * 512];
  __shared__ __align__(16) f16 Ws[10 * 512];
  __shared__ float bsum[160], bsq[160];

  int t = threadIdx.x;
  int w = t >> 6, l = t & 63;
  int wr = w >> 1, wc = w & 1;
  int l15 = l & 15, l4 = l >> 4;
  int RB0 = blockIdx.x * 8;

  if (LAYER && t < 160) { bsum[t] = 0.f; bsq[t] = 0.f; }

  f32x4 acc[4][5];
#pragma unroll
  for (int i = 0; i < 4; ++i)
#pragma unroll
    for (int j = 0; j < 5; ++j) acc[i][j] = (f32x4)0.f;

#pragma unroll 1
  for (int s = 0; s < NSTEP; ++s) {
    __syncthreads();
#pragma unroll
    for (int u = 0; u < 2; ++u) {
      int i = t + u * 256;
      int rb = i >> 6, p = i & 63;
      int RB = RB0 + rb;
      f16x8 v = (f16x8)(f16)0;
      if (RB < NRB) v = *(const f16x8*)(At + ((size_t)RB * KG + 4 * s) * 128 + p * 8);
      *(f16x8*)(As + rb * 512 + p * 8) = v;
    }
#pragma unroll
    for (int u = 0; u < 3; ++u) {
      int m = t + u * 256;
      if (m < 640) {
        int cb = m >> 6, p = m & 63;
        f16x8 v = *(const f16x8*)(Wt + ((size_t)cb * KG + 4 * s) * 128 + p * 8);
        *(f16x8*)(Ws + cb * 512 + p * 8) = v;
      }
    }
    __syncthreads();

    f16x8 af[4], bf[5];
#pragma unroll
    for (int i = 0; i < 4; ++i)
      af[i] = *(const f16x8*)(As + (wr * 4 + i) * 512 + l4 * 128 + l15 * 8);
#pragma unroll
    for (int j = 0; j < 5; ++j)
      bf[j] = *(const f16x8*)(Ws + (wc * 5 + j) * 512 + l4 * 128 + l15 * 8);
#pragma unroll
    for (int i = 0; i < 4; ++i)
#pragma unroll
      for (int j = 0; j < 5; ++j)
        acc[i][j] = __builtin_amdgcn_mfma_f32_16x16x32_f16(af[i], bf[j], acc[i][j], 0, 0, 0);
  }

  float cs[5], cq[5];
#pragma unroll
  for (int j = 0; j < 5; ++j) { cs[j] = 0.f; cq[j] = 0.f; }

  int colbase = wc * 80;
  int rowbase = RB0 * 16 + wr * 64;
#pragma unroll
  for (int i = 0; i < 4; ++i) {
#pragma unroll
    for (int r = 0; r < 4; ++r) {
      int row = rowbase + i * 16 + l4 * 4 + r;
      bool ok = row < NN;
      float sn = 1.f;
      if (LAYER && ok) sn = snorm[row];
#pragma unroll
      for (int j = 0; j < 5; ++j) {
        int col = colbase + j * 16 + l15;
        float v = acc[i][j][r] + bp[col];
        if (LAYER) {
          v *= sn;
          if (ok) {
            Ch[(size_t)row * 160 + col] = (f16)v;
            cs[j] += v;
            cq[j] = fmaf(v, v, cq[j]);
          }
        } else {
          if (ok) {
            if (col < HD) Hh[(size_t)row * SP + col] = (f16)v;
            else if (col < SP) Hh[(size_t)row * SP + col] = (f16)0;
          }
        }
      }
    }
  }
  if (LAYER) {
#pragma unroll
    for (int j = 0; j < 5; ++j) {
      int col = colbase + j * 16 + l15;
      atomicAdd(&bsum[col], cs[j]);
      atomicAdd(&bsq[col], cq[j]);
    }
    __syncthreads();
    if (t < 160) {
      stp[(size_t)blockIdx.x * 320 + t] = bsum[t];
      stp[(size_t)blockIdx.x * 320 + 160 + t] = bsq[t];
    }
  }
}

// reduce stp[GB][320] -> stsum[320]
__global__ void k_stred(const float* __restrict__ stp, float* __restrict__ stsum) {
  int c = blockIdx.x;
  int t = threadIdx.x;
  float s = 0.f;
  for (int i = t; i < GB; i += 128) s += stp[(size_t)i * 320 + c];
  __shared__ float sm[128];
  sm[t] = s; __syncthreads();
  for (int o = 64; o > 0; o >>= 1) {
    if (t < o) sm[t] += sm[t + o];
    __syncthreads();
  }
  if (t == 0) stsum[c] = sm[0];
}

// ---------------- update (BN finalize fused): hh += relu(h2*a+b2), f16x8 ----------------
__global__ __launch_bounds__(256) void k_update(const f16* __restrict__ h2,
    const float* __restrict__ st, const float* __restrict__ g,
    const float* __restrict__ bt, f16* __restrict__ hh) {
  __shared__ float ab[320];
  int t = threadIdx.x;
  if (t < 160) {
    float m = st[t] * (1.f / NN);
    float q = st[160 + t] * (1.f / NN);
    float iv = rsqrtf(q - m * m + EPSF);
    float gg = (t < HD) ? g[t] : 0.f;
    float bb = (t < HD) ? bt[t] : 0.f;
    float a = iv * gg;
    ab[t] = a;
    ab[160 + t] = bb - m * a;
  }
  __syncthreads();
  const int total = NN * 19;     // 19 x f16x8 groups = cols 0..151
  int stride = gridDim.x * 256;
  for (int idx = blockIdx.x * 256 + t; idx < total; idx += stride) {
    int r = idx / 19, gq = idx - r * 19;
    int c = gq * 8;
    f16x8 p = *(const f16x8*)(h2 + (size_t)r * 160 + c);
    f16x8 hv = *(const f16x8*)(hh + (size_t)r * SP + c);
    f16x8 ho;
#pragma unroll
    for (int j = 0; j < 8; ++j) {
      float v = fmaf((float)p[j], ab[c + j], ab[160 + c + j]);
      float hn = (float)hv[j] + fmaxf(v, 0.f);
      ho[j] = (f16)hn;
    }
    *(f16x8*)(hh + (size_t)r * SP + c) = ho;
  }
}

// ---------------- readout: per-chunk partials (no global atomics) ----------------
__global__ __launch_bounds__(256) void k_readout1(const f16* __restrict__ hh,
    const int* __restrict__ gb, float* __restrict__ out16) {
  int g = blockIdx.x >> 4, chunk = blockIdx.x & 15;
  int lo = gb[g], hi = gb[g + 1];
  int w = threadIdx.x >> 6, lane = threadIdx.x & 63;
  __shared__ float sacc[148];
  if (threadIdx.x < 148) sacc[threadIdx.x] = 0.f;
  __syncthreads();
  f32x4 acc = (f32x4)0.f;
  if (lane < 37) {
    for (int r = lo + chunk * 4 + w; r < hi; r += 64) {
      f16x4 v = *(const f16x4*)(hh + (size_t)r * SP + lane * 4);
      acc[0] += (float)v[0];
      acc[1] += (float)v[1];
      acc[2] += (float)v[2];
      acc[3] += (float)v[3];
    }
    atomicAdd(&sacc[lane * 4 + 0], acc[0]);
    atomicAdd(&sacc[lane * 4 + 1], acc[1]);
    atomicAdd(&sacc[lane * 4 + 2], acc[2]);
    atomicAdd(&sacc[lane * 4 + 3], acc[3]);
  }
  __syncthreads();
  if (threadIdx.x < 148)
    out16[((size_t)chunk * NG + g) * 148 + threadIdx.x] = sacc[threadIdx.x];
}

__global__ void k_rdiv(const int* __restrict__ gb, const float* __restrict__ out16,
                       float* __restrict__ out) {
  int g = blockIdx.x, c = threadIdx.x;
  if (c < HD) {
    float s = 0.f;
#pragma unroll
    for (int ch = 0; ch < 16; ++ch) s += out16[((size_t)ch * NG + g) * 148 + c];
    out[g * HD + c] = s / fmaxf((float)(gb[g + 1] - gb[g]), 1.f);
  }
}

extern "C" void kernel_launch(void* const* d_in, const int* in_sizes, int n_in,
                              void* d_out, int out_size, void* d_ws, size_t ws_size,
                              hipStream_t stream) {
  const float* X     = (const float*)d_in[0];
  const float* snorm = (const float*)d_in[1];
  const float* W_e   = (const float*)d_in[2];
  const float* b_e   = (const float*)d_in[3];
  const float* Wl[3]  = {(const float*)d_in[4], (const float*)d_in[8],  (const float*)d_in[12]};
  const float* bl[3]  = {(const float*)d_in[5], (const float*)d_in[9],  (const float*)d_in[13]};
  const float* gl[3]  = {(const float*)d_in[6], (const float*)d_in[10], (const float*)d_in[14]};
  const float* btl[3] = {(const float*)d_in[7], (const float*)d_in[11], (const float*)d_in[15]};
  const int* src = (const int*)d_in[16];
  const int* dst = (const int*)d_in[17];
  const int* gid = (const int*)d_in[18];
  float* out = (float*)d_out;

  char* p = (char*)d_ws;
  f16* hh    = (f16*)p;   p += sizeof(f16) * (size_t)NN * SP;          // 30.4 MB
  f16* aggt  = (f16*)p;   p += sizeof(f16) * (size_t)NRB * 20 * 128;   // 32 MB (Xt & h2 alias)
  f16* WtE   = (f16*)p;   p += sizeof(f16) * 10240;
  f16* Wt    = (f16*)p;   p += sizeof(f16) * 3 * 25600;
  float* bp  = (float*)p; p += sizeof(float) * 4 * 160;
  float* stp = (float*)p; p += sizeof(float) * (size_t)GB * 320;       // 1 MB
  float* stsum = (float*)p; p += sizeof(float) * 320;
  float* out16 = (float*)p; p += sizeof(float) * 16 * NG * 148;        // 2.4 MB
  float* ns  = (float*)p; p += sizeof(float) * NN;
  float* nd  = (float*)p; p += sizeof(float) * NN;
  int* cnt  = (int*)p; p += sizeof(int) * NN;                          // in-degree
  int* cs8  = (int*)p; p += sizeof(int) * 8 * NN;                      // out-deg partials (XCD-local)
  int* gb   = (int*)p; p += sizeof(int) * (NG + 1);
  int* buck = (int*)p; p += sizeof(int) * (size_t)NN * BCAP;           // 25.6 MB

  f16* Xt = aggt;
  f16* h2 = aggt;

  hipMemsetAsync(cnt, 0, sizeof(int) * 9 * (size_t)NN, stream);   // cnt & cs8 contiguous

  const int EB = (NE + 255) / 256;
  k_build<<<EB, 256, 0, stream>>>(src, dst, cnt, buck, cs8);
  k_norms<<<NSB, 256, 0, stream>>>(cs8, cnt, ns, nd);

  k_prep<<<345, 256, 0, stream>>>(W_e, Wl[0], Wl[1], Wl[2], b_e, bl[0], bl[1], bl[2],
                                  WtE, Wt, bp, gid, gb);

  k_convX<<<(NRB * 8 * 16 + 255) / 256, 256, 0, stream>>>(X, Xt);
  k_mfma<8, 2, false><<<GB, 256, 0, stream>>>(Xt, WtE, bp, nullptr, hh, nullptr, nullptr);

  for (int l = 0; l < 3; ++l) {
    k_pull<<<(NN * 64 + 255) / 256, 256, 0, stream>>>(hh, ns, nd, cnt, buck, aggt);
    k_mfma<20, 5, true><<<GB, 256, 0, stream>>>(aggt, Wt + l * 25600, bp + (l + 1) * 160,
                                                snorm, nullptr, h2, stp);
    k_stred<<<320, 128, 0, stream>>>(stp, stsum);
    k_update<<<4096, 256, 0, stream>>>(h2, stsum, gl[l], btl[l], hh);
  }

  k_readout1<<<NG * 16, 256, 0, stream>>>(hh, gb, out16);
  k_rdiv<<<NG, 192, 0, stream>>>(gb, out16, out);
}